// Round 2
// 256.083 us; speedup vs baseline: 1.2683x; 1.2683x over previous
//
#include <hip/hip_runtime.h>
#include <hip/hip_bf16.h>

#define NB 8
#define LIN_SCALE 0.044194173824159216f
#define SCALE 0.014731391274719736f

typedef __attribute__((ext_vector_type(8))) short short8;
typedef __attribute__((ext_vector_type(4))) float floatx4;

// ---------------- workspace layout (bytes) ----------------
static constexpr size_t O_XS   = 0;                   // 8*34*34*512 bf16 (zero-padded NHWC modulated x)
static constexpr size_t O_OUT1 = 9469952;             // parity planes bf16: 34,611,200
static constexpr size_t O_WRT  = 44081152;            // 9*512*512 bf16 wrt[tap][o][i]
static constexpr size_t O_WB   = 48799744;            // 512*4608 bf16 wb[o][k]
static constexpr size_t O_PG   = 53518336;            // 8*512*512 f32 gram partials (also: loss partials pre-k_mfma)
static constexpr size_t O_WSQ  = 61906944;            // 512*512 f32
static constexpr size_t O_CL   = 62955520;            // (unused now; kept for layout stability)
static constexpr size_t O_GR   = O_CL + 32768;
static constexpr size_t O_SB   = O_GR + 32768;
static constexpr size_t O_ST0  = O_SB + 1024;
static constexpr size_t O_STS  = O_ST0 + 16384;
static constexpr size_t O_ST2  = O_STS + 16384;
static constexpr size_t O_WNI  = O_ST2 + 16384;
static constexpr size_t O_DM   = O_WNI + 2048;
static constexpr size_t O_ACC  = O_DM + 16384;

static constexpr size_t OUT_CO = 16777216;            // d_out offset of co_out (floats)
static constexpr size_t OUT_L  = 17039360;            // d_out offset of losses (floats)

// parity-class tables for the transposed conv (gather form, wf[k]=W[2-k] folded)
__device__ const int c_ylim[4] = {33,33,32,32};
__device__ const int c_xlim[4] = {33,32,33,32};
__device__ const int c_ntap[4] = {4,2,2,1};
__device__ const int c_tap0[4] = {0,4,6,8};
__device__ const int c_nmb[4]  = {69,66,66,64};       // ceil(M/128)
__device__ const int c_cnt[4]  = {276,264,264,256};   // nmb*4
__device__ const int c_dy[9] = {-1,-1,0,0, -1,0, 0,0, 0};
__device__ const int c_dx[9] = {-1,0,-1,0, 0,0, -1,0, 0};
__device__ const int c_ky[9] = {2,2,0,0, 2,0, 1,1, 1};
__device__ const int c_kx[9] = {2,0,2,0, 1,1, 2,0, 1};
__device__ const long c_poff[4] = {0, 4460544, 8785920, 13111296};

__device__ __forceinline__ float wave_red(float v) {
#pragma unroll
  for (int s = 32; s > 0; s >>= 1) v += __shfl_down(v, s);
  return v;
}

__device__ __forceinline__ void gl_lds16(const void* g, void* l) {
  __builtin_amdgcn_global_load_lds((const __attribute__((address_space(1))) void*)g,
                                   (__attribute__((address_space(3))) void*)l, 16, 0, 0);
}

__device__ __forceinline__ unsigned short bf16b(float f) {
  union { __hip_bfloat16 h; unsigned short u; } cv;
  cv.h = __float2bfloat16(f);
  return cv.u;
}

__device__ __forceinline__ float bfu(unsigned short u) {
  union { float f; unsigned u32; } c; c.u32 = ((unsigned)u) << 16; return c.f;
}

// bijective chunked XCD swizzle (m204): blocks with same (lb&7) sit on one XCD
// (lb = bid - segment_base, constant base => constant physical XCD); give each
// XCD a CONTIGUOUS logical range within the segment.
__device__ __forceinline__ int xcd_chunk(int lb, int cnt) {
  const int q = cnt >> 3, r = cnt & 7;
  const int c = lb & 7, i = lb >> 3;
  return (c < r) ? c*(q+1) + i : r*(q+1) + (c - r)*q + i;
}

// ---------------- K2': wproc(512) + st0(64) + losses(512) + prep(1) + xs-border-zero(12) ----------------
__global__ __launch_bounds__(256) void k_big1(const float* __restrict__ W,
    float* __restrict__ wsq, float* __restrict__ wni,
    __hip_bfloat16* __restrict__ wrt, unsigned short* __restrict__ wb,
    const float* __restrict__ style, const float* __restrict__ mod_w,
    const float* __restrict__ mod_b, float* __restrict__ st0,
    const float* __restrict__ co, const float* __restrict__ gate,
    const float* __restrict__ cluster, const float* __restrict__ tmpr,
    const float* __restrict__ mb_w, const float* __restrict__ mb_b,
    float* __restrict__ gr, float* __restrict__ sb,
    float* __restrict__ pacc, __hip_bfloat16* __restrict__ xs) {
  __shared__ float sh[8192];
  __shared__ float extra[8];
  const int bid = blockIdx.x, tid = threadIdx.x;
  const int lane = tid & 63, wv = tid >> 6;
  if (bid < 512) {
    const int o = bid;
    for (int j = tid; j < 4608; j += 256) sh[j] = W[(size_t)o*4608 + j];
    __syncthreads();
    float tot = 0.f;
#pragma unroll
    for (int half = 0; half < 2; half++) {
      const int i = tid + half*256;
      float s = 0.f;
#pragma unroll
      for (int k = 0; k < 9; k++) { float w = sh[i*9 + k]; s = fmaf(w, w, s); }
      wsq[o*512 + i] = s; tot += s;
#pragma unroll
      for (int tp = 0; tp < 9; tp++)
        wrt[((size_t)tp*512 + o)*512 + i] = __float2bfloat16(sh[i*9 + c_ky[tp]*3 + c_kx[tp]]);
    }
    for (int j = tid; j < 4608; j += 256) wb[(size_t)o*4608 + j] = bf16b(sh[j]);
    tot = wave_red(tot);
    if (lane == 0) extra[wv] = tot;
    __syncthreads();
    if (tid == 0) wni[o] = 1.f / fmaxf(sqrtf(extra[0]+extra[1]+extra[2]+extra[3]), 1e-12f);
  } else if (bid < 576) {
    const int b = (bid - 512) >> 3, oc = (bid - 512) & 7;
    sh[tid] = style[b*1024 + 512 + tid];
    sh[tid + 256] = style[b*1024 + 768 + tid];
    __syncthreads();
#pragma unroll
    for (int rr = 0; rr < 16; rr++) {
      const int c = oc*64 + wv*16 + rr;
      const float* mw = mod_w + (size_t)c*512;
      float acc = 0.f;
#pragma unroll
      for (int it = 0; it < 8; it++) acc = fmaf(mw[lane + 64*it], sh[lane + 64*it], acc);
      acc = wave_red(acc);
      if (lane == 0) st0[b*512 + c] = acc*LIN_SCALE + mod_b[c];
    }
  } else if (bid < 1088) {
    // losses: recompute cl locally (removes serial k_prep dependency)
    const int i = bid - 576;
    const float tt = 5.f / (1.f + expf(-tmpr[0]));
    const float gg = 1.f / (1.f + expf(-gate[0]));
    for (int j = tid; j < 512; j += 256) {
      float v[16]; float m = -1e30f;
#pragma unroll
      for (int g = 0; g < 16; g++) { v[g] = tt * cluster[g*512 + j]; m = fmaxf(m, v[g]); }
      float s = 0.f;
#pragma unroll
      for (int g = 0; g < 16; g++) { v[g] = expf(v[g] - m); s += v[g]; }
      float inv = 1.f / s;
#pragma unroll
      for (int g = 0; g < 16; g++) sh[g*512 + j] = v[g] * inv;
    }
    __syncthreads();
    float cli[16];
#pragma unroll
    for (int k = 0; k < 16; k++) cli[k] = sh[k*512 + i];
    float p1 = 0.f, p2 = 0.f;
    for (int j = tid; j < 512; j += 256) {
      float d = 0.f;
#pragma unroll
      for (int k = 0; k < 16; k++) d = fmaf(cli[k], sh[k*512 + j], d);
      float S = 1.f / (1.f + expf(-50.f*(co[i*512 + j] - gg)));
      float e = d - S;
      p1 = fmaf(e, e, p1); p2 += S;
    }
    p1 = wave_red(p1); p2 = wave_red(p2);
    if (lane == 0) { extra[wv] = p1; extra[4 + wv] = p2; }
    __syncthreads();
    if (tid == 0)  pacc[i]       = extra[0]+extra[1]+extra[2]+extra[3];
    if (tid == 64) pacc[512 + i] = extra[4]+extra[5]+extra[6]+extra[7];
  } else if (bid == 1088) {
    // prep: gr + sb (old k_prep minus cl-global and accs)
    const float tt = 5.f / (1.f + expf(-tmpr[0]));
#pragma unroll
    for (int h = 0; h < 2; h++) {
      const int c = tid + h*256;
      float v[16]; float m = -1e30f;
#pragma unroll
      for (int g = 0; g < 16; g++) { v[g] = tt * cluster[g*512 + c]; m = fmaxf(m, v[g]); }
      float s = 0.f;
#pragma unroll
      for (int g = 0; g < 16; g++) { v[g] = expf(v[g] - m); s += v[g]; }
      float inv = 1.f / s;
      float clv[16]; float m2 = -1e30f;
#pragma unroll
      for (int g = 0; g < 16; g++) { clv[g] = v[g]*inv; m2 = fmaxf(m2, 500.f*clv[g]); }
      float s2 = 0.f; float e2[16];
#pragma unroll
      for (int g = 0; g < 16; g++) { e2[g] = expf(500.f*clv[g] - m2); s2 += e2[g]; }
      float i2 = 1.f / s2;
#pragma unroll
      for (int g = 0; g < 16; g++) gr[g*512 + c] = rintf(e2[g]*i2) + 1e-6f;
    }
    for (int task = wv; task < 128; task += 4) {
      int b = task >> 4, g = task & 15;
      const float* s1 = style + b*1024;
      const float* mw = mb_w + g*512;
      float acc = 0.f;
#pragma unroll
      for (int it = 0; it < 8; it++) acc = fmaf(s1[lane + 64*it], mw[lane + 64*it], acc);
      acc = wave_red(acc);
      if (lane == 0) sb[b*16 + g] = acc*LIN_SCALE + mb_b[g];
    }
  } else {
    // zero the xs border ring (replaces the 9.5 MB memset; 1.08 MB actual)
    const int id0 = (bid - 1089)*256 + tid;
    const float4 z = make_float4(0.f, 0.f, 0.f, 0.f);
    float4* xq = (float4*)xs;
#pragma unroll
    for (int it = 0; it < 22; ++it) {
      const int id = id0 + it*3072;          // 12 blocks * 256 thr * 22 = 67584 float4s
      const int c = id & 63;
      const int pb = id >> 6;                // 0..1055
      const int b = pb / 132;
      const int pix = pb - b*132;
      int y, xx;
      if (pix < 34)       { y = 0;        xx = pix; }
      else if (pix < 68)  { y = 33;       xx = pix - 34; }
      else if (pix < 100) { y = pix - 67; xx = 0; }
      else                { y = pix - 99; xx = 33; }
      xq[((size_t)(b*34 + y)*34 + xx)*64 + c] = z;
    }
  }
}

// ---------------- K3: style mix (8 blocks) + loss-partial reduce (1 block) ----------------
__global__ __launch_bounds__(256) void k_mix(const float* __restrict__ st0,
    const float* __restrict__ gr, const float* __restrict__ sb,
    float* __restrict__ sts, float* __restrict__ st2,
    const float* __restrict__ pacc, float* __restrict__ out_tail) {
  if (blockIdx.x == 8) {
    const int tid = threadIdx.x;
    const int lane = tid & 63, wv = tid >> 6;
    __shared__ float r1[4], r2[4];
    float a = pacc[tid] + pacc[tid + 256];
    float b = pacc[512 + tid] + pacc[768 + tid];
    a = wave_red(a); b = wave_red(b);
    if (lane == 0) { r1[wv] = a; r2[wv] = b; }
    __syncthreads();
    if (tid == 0) {
      float p1 = r1[0]+r1[1]+r1[2]+r1[3];
      float p2 = r2[0]+r2[1]+r2[2]+r2[3];
      out_tail[0] = p1;
      float d = 16384.f - p2;
      out_tail[1] = d*d;
    }
    return;
  }
  const int b = blockIdx.x, tid = threadIdx.x;
  const int lane = tid & 63, wv = tid >> 6;
  float s0 = st0[b*512 + tid], s1 = st0[b*512 + 256 + tid];
  float g0[16], g1[16];
#pragma unroll
  for (int g = 0; g < 16; g++) { g0[g] = gr[g*512 + tid]; g1[g] = gr[g*512 + 256 + tid]; }
  __shared__ float red[16][4];
  __shared__ float inv[16];
  __shared__ float sbb[16];
#pragma unroll
  for (int g = 0; g < 16; g++) {
    float a = g0[g]*s0, c = g1[g]*s1;
    float p = wave_red(a*a + c*c);
    if (lane == 0) red[g][wv] = p;
  }
  if (tid < 16) sbb[tid] = sb[b*16 + tid];
  __syncthreads();
  if (tid < 16) {
    float tt = red[tid][0] + red[tid][1] + red[tid][2] + red[tid][3];
    inv[tid] = 1.f / fmaxf(sqrtf(tt), 1e-12f);
  }
  __syncthreads();
  float f0 = 0.f, f1 = 0.f;
#pragma unroll
  for (int g = 0; g < 16; g++) {
    float w = inv[g]*sbb[g];
    f0 = fmaf(g0[g], w, f0); f1 = fmaf(g1[g], w, f1);
  }
  float sn0 = s0*f0, sn1 = s1*f1;
  sts[b*512 + tid] = sn0*SCALE;        st2[b*512 + tid] = sn0*sn0;
  sts[b*512 + 256 + tid] = sn1*SCALE;  st2[b*512 + 256 + tid] = sn1*sn1;
}

// ---------------- K4: demod(64) + xsprep(1024), 1088 blocks ----------------
__global__ __launch_bounds__(256) void k_big2(const float* __restrict__ st2,
    const float* __restrict__ wsq, float* __restrict__ dm,
    const float* __restrict__ x, const float* __restrict__ sts,
    __hip_bfloat16* __restrict__ xs) {
  __shared__ float L[64*65];
  const int tid = threadIdx.x;
  const int lane = tid & 63, wv = tid >> 6;
  if (blockIdx.x < 64) {
    const int b = blockIdx.x >> 3, oc = blockIdx.x & 7;
    L[tid] = st2[b*512 + tid];
    L[tid + 256] = st2[b*512 + 256 + tid];
    __syncthreads();
#pragma unroll
    for (int rr = 0; rr < 16; rr++) {
      const int o = oc*64 + wv*16 + rr;
      const float* wp = wsq + (size_t)o*512;
      float acc = 0.f;
#pragma unroll
      for (int it = 0; it < 8; it++) acc = fmaf(wp[lane + 64*it], L[lane + 64*it], acc);
      acc = wave_red(acc);
      if (lane == 0) dm[b*512 + o] = rsqrtf((1.0f/4608.0f)*acc + 1e-8f);
    }
    return;
  }
  const int id = blockIdx.x - 64;
  const int b = id >> 7;
  const int p0 = ((id >> 3) & 15) * 64;
  const int i0 = (id & 7) * 64;
  const int lp = tid & 63, li = tid >> 6;
  const float* xp = x + ((size_t)b*512 + i0)*1024 + p0;
#pragma unroll
  for (int ii = 0; ii < 16; ii++) {
    const int i = li + 4*ii;
    L[i*65 + lp] = xp[(size_t)i*1024 + lp];
  }
  __syncthreads();
  const int iw = tid & 63, pw = tid >> 6;
  const float sv = sts[b*512 + i0 + iw];
#pragma unroll
  for (int pp = 0; pp < 16; pp++) {
    const int pix = p0 + pw + 4*pp;
    const int y = pix >> 5, xq = pix & 31;
    xs[(((size_t)b*34 + (y+1))*34 + (xq+1))*512 + i0 + iw] = __float2bfloat16(L[iw*65 + pw + 4*pp] * sv);
  }
}

// ---------------- K5: conv MFMA (1060) + gram MFMA (128), 1188 blocks ----------------
// LDS: A[128][32]bf16 @0..4095, B[128][32] @4096..8191 (elements), XOR-swizzled:
//   logical (row,quad16B) stored at physical (row ^ ((row>>2)&1), quad ^ (row&3))
//   -> each quarter-wave of ds_read_b128 covers all 8 LDS 16B-slots exactly 2x (free).
// Staging keeps the LDS dest LINEAR (global_load_lds requirement) and pre-swizzles
// the per-lane GLOBAL source address (the m173 pattern). Epilogue Ct[64][136] unchanged.
__global__ __launch_bounds__(256, 4) void k_mfma(
    const __hip_bfloat16* __restrict__ xs, const __hip_bfloat16* __restrict__ wrt,
    __hip_bfloat16* __restrict__ out1, const __hip_bfloat16* __restrict__ wb,
    float* __restrict__ pgram) {
  __shared__ __hip_bfloat16 smem[8704];
  const int fid = blockIdx.x;
  const int tid = threadIdx.x;
  const int lane = tid & 63, wv = tid >> 6;
  const int wm = (wv >> 1) << 6, wn = (wv & 1) << 6;
  const int col16 = lane & 15, quad = lane >> 4;
  // swizzled fragment-read offsets (logical row = wm+t*16+col16, k-octet = quad)
  const int colp = col16 ^ ((col16 >> 2) & 1);
  const int soff = (quad ^ (col16 & 3)) << 3;

  int aoff[4], boff[4];
#pragma unroll
  for (int t = 0; t < 4; t++) {
    aoff[t] = (wm + t*16 + colp)*32 + soff;
    boff[t] = 4096 + (wn + t*16 + colp)*32 + soff;
  }
  floatx4 acc[4][4];
#pragma unroll
  for (int i = 0; i < 4; i++)
#pragma unroll
    for (int j = 0; j < 4; j++) acc[i][j] = (floatx4){0.f, 0.f, 0.f, 0.f};

  if (fid >= 276 && fid < 404) {
    // ---- gram: wn_gram @ wn_gram^T partial, split-K=8 ----
    // chunked XCD swizzle: each XCD owns one kz slice (576 KB of wb, L2-resident)
    const int g = xcd_chunk(fid - 276, 128);
    const int m0 = (g & 3) * 128, n0 = ((g >> 2) & 3) * 128;
    const long kz = (long)(g >> 4) * 576;
    long abase[2], bbase[2]; int ldso[2];
#pragma unroll
    for (int r = 0; r < 2; r++) {
      const int idx = r*256 + tid;
      const int rowp = idx >> 2;
      const int row = rowp ^ ((rowp >> 2) & 1);            // inverse LDS swizzle:
      const int kc = (((idx & 3) ^ (row & 3)) << 3);       // this chunk holds (row,kc)
      abase[r] = (long)(m0 + row)*4608 + kz + kc;
      bbase[r] = (long)(n0 + row)*4608 + kz + kc;
      ldso[r] = idx << 3;
    }
    for (int ks = 0; ks < 18; ks++) {
      const int kk = ks << 5;
#pragma unroll
      for (int r = 0; r < 2; r++) {
        gl_lds16(wb + (abase[r] + kk), smem + ldso[r]);
        gl_lds16(wb + (bbase[r] + kk), smem + 4096 + ldso[r]);
      }
      __syncthreads();
      short8 af[4], bf[4];
#pragma unroll
      for (int t = 0; t < 4; t++) {
        af[t] = *(const short8*)(smem + aoff[t]);
        bf[t] = *(const short8*)(smem + boff[t]);
      }
#pragma unroll
      for (int i = 0; i < 4; i++)
#pragma unroll
        for (int j = 0; j < 4; j++)
          acc[i][j] = __builtin_amdgcn_mfma_f32_16x16x32_bf16(af[i], bf[j], acc[i][j], 0, 0, 0);
      __syncthreads();
    }
    float* pg = pgram + (size_t)(g >> 4) * 262144;
#pragma unroll
    for (int i = 0; i < 4; i++)
#pragma unroll
      for (int j = 0; j < 4; j++) {
        const int m = m0 + wm + i*16 + (quad << 2);
        const int n = n0 + wn + j*16 + col16;
#pragma unroll
        for (int r = 0; r < 4; r++) pg[(size_t)(m + r)*512 + n] = acc[i][j][r];
      }
    return;
  }

  // ---- conv ----
  int cls, lb;
  if (fid < 276)      { cls = 0; lb = fid; }
  else if (fid < 668) { cls = 1; lb = fid - 404; }
  else if (fid < 932) { cls = 2; lb = fid - 668; }
  else                { cls = 3; lb = fid - 932; }
  // per-class chunked XCD swizzle (keeps XCD work balanced across classes),
  // mb-major order: 4 consecutive logical blocks share the A-tile -> L2 reuse.
  const int lg = xcd_chunk(lb, c_cnt[cls]);
  const int mb = lg >> 2, nb = lg & 3;
  const int xlim = c_xlim[cls];
  const int npix = c_ylim[cls] * xlim;
  const int M = NB * npix;
  const int m0 = mb * 128, n0 = nb * 128;
  const int t0 = c_tap0[cls];
  const int ntap = c_ntap[cls];

  long abase[2], bbase[2]; int ldso[2];
#pragma unroll
  for (int r = 0; r < 2; r++) {
    const int idx = r*256 + tid;
    const int rowp = idx >> 2;
    const int row = rowp ^ ((rowp >> 2) & 1);              // inverse LDS swizzle
    const int kc = (((idx & 3) ^ (row & 3)) << 3);
    int rm = m0 + row; if (rm >= M) rm = 0;
    const int b = rm / npix; const int rem = rm - b*npix;
    const int yy = rem / xlim; const int xx = rem - yy*xlim;
    abase[r] = ((long)(b*34 + yy + 1)*34 + (xx + 1))*512 + kc;
    bbase[r] = ((long)(t0*512 + n0 + row))*512 + kc;
    ldso[r] = idx << 3;
  }

  for (int tp = 0; tp < ntap; tp++) {
    const int tap = t0 + tp;
    const long adel = (long)((c_dy[tap]*34 + c_dx[tap])*512);
    const long bdel = (long)tp << 18;
    for (int ks = 0; ks < 16; ks++) {
      const int kk = ks << 5;
#pragma unroll
      for (int r = 0; r < 2; r++) {
        gl_lds16(xs + (abase[r] + adel + kk), smem + ldso[r]);
        gl_lds16(wrt + (bbase[r] + bdel + kk), smem + 4096 + ldso[r]);
      }
      __syncthreads();
      short8 af[4], bf[4];
#pragma unroll
      for (int t = 0; t < 4; t++) {
        af[t] = *(const short8*)(smem + aoff[t]);
        bf[t] = *(const short8*)(smem + boff[t]);
      }
#pragma unroll
      for (int i = 0; i < 4; i++)
#pragma unroll
        for (int j = 0; j < 4; j++)
          acc[i][j] = __builtin_amdgcn_mfma_f32_16x16x32_bf16(af[i], bf[j], acc[i][j], 0, 0, 0);
      __syncthreads();
    }
  }

  // two-pass epilogue: transpose 64 n-cols at a time through Ct[64][136]
  __hip_bfloat16* plane = out1 + c_poff[cls];
#pragma unroll
  for (int h = 0; h < 2; h++) {
    if ((wv & 1) == h) {
#pragma unroll
      for (int i = 0; i < 4; i++) {
        const int mrow = wm + i*16 + (quad << 2);
#pragma unroll
        for (int j = 0; j < 4; j++) {
          const int ncl = j*16 + col16;               // local col in [0,64)
          ushort4 v;
          v.x = bf16b(acc[i][j][0]); v.y = bf16b(acc[i][j][1]);
          v.z = bf16b(acc[i][j][2]); v.w = bf16b(acc[i][j][3]);
          *(ushort4*)(smem + ncl*136 + mrow) = v;
        }
      }
    }
    __syncthreads();
#pragma unroll
    for (int it = 0; it < 4; it++) {
      const int c = it*256 + tid;
      const int ol = c >> 4, ml = (c & 15) << 3;
      const int mg = m0 + ml;
      if (mg < M) {
        const ushort4 v = *(const ushort4*)(smem + ol*136 + ml);
        *(ushort4*)(plane + (long)(n0 + h*64 + ol)*M + mg) = v;
      }
    }
    __syncthreads();
  }
}

// ---------------- K7: gram reduce+normalize (256) + blur+epilogue (4096) ----------------
__global__ __launch_bounds__(256) void k_blur(const __hip_bfloat16* __restrict__ out1,
    const float* __restrict__ dm, const float* __restrict__ noise,
    const float* __restrict__ nw, const float* __restrict__ fb, float* __restrict__ out,
    const float* __restrict__ pgram, const float* __restrict__ wni,
    float* __restrict__ co_out) {
  if (blockIdx.x < 256) {
    const int i4 = blockIdx.x*256 + threadIdx.x;      // 65536 float4s
    float4 s = make_float4(0.f, 0.f, 0.f, 0.f);
#pragma unroll
    for (int z = 0; z < 8; z++) {
      const float4 v = ((const float4*)(pgram + (size_t)z*262144))[i4];
      s.x += v.x; s.y += v.y; s.z += v.z; s.w += v.w;
    }
    const float wm = wni[i4 >> 7];
    const float4 wn4 = ((const float4*)wni)[i4 & 127];
    float4 o;
    o.x = s.x*wm*wn4.x; o.y = s.y*wm*wn4.y; o.z = s.z*wm*wn4.z; o.w = s.w*wm*wn4.w;
    ((float4*)co_out)[i4] = o;
    return;
  }
  const int bo = blockIdx.x - 256;
  const int b = bo >> 9, o = bo & 511;
  __shared__ unsigned short L[65 * 68];   // [m][q+1], cols 0 and 66 are zero guards
  const int tid = threadIdx.x;
  const unsigned short* p0 = (const unsigned short*)out1 + 0        + (long)o * 8712 + b * 1089;
  const unsigned short* p1 = (const unsigned short*)out1 + 4460544  + (long)o * 8448 + b * 1056;
  const unsigned short* p2 = (const unsigned short*)out1 + 8785920  + (long)o * 8448 + b * 1056;
  const unsigned short* p3 = (const unsigned short*)out1 + 13111296 + (long)o * 8192 + b * 1024;
  for (int m = tid; m < 65; m += 256) { L[m*68 + 0] = 0; L[m*68 + 66] = 0; }
  for (int e = tid; e < 1089; e += 256) { int y = e / 33, x = e - 33*y; L[(2*y)*68 + 2*x + 1] = p0[e]; }
  for (int e = tid; e < 1056; e += 256) { int y = e >> 5, x = e & 31;   L[(2*y)*68 + 2*x + 2] = p1[e]; }
  for (int e = tid; e < 1056; e += 256) { int y = e / 33, x = e - 33*y; L[(2*y+1)*68 + 2*x + 1] = p2[e]; }
  for (int e = tid; e < 1024; e += 256) { int y = e >> 5, x = e & 31;   L[(2*y+1)*68 + 2*x + 2] = p3[e]; }
  __syncthreads();
  const float dmv = dm[bo];
  const float nwv = nw[0];
  const float bv = fb[o];
  const int Q = tid & 63;
  const int qy = tid >> 6;
  const int mbase = 16 * qy - 1;
  float hs[18];
#pragma unroll
  for (int rm = 0; rm < 18; rm++) {
    const int m = mbase + rm;
    float s = 0.f;
    if (m >= 0 && m <= 64) {
      const unsigned short* row = L + m*68 + Q;
      s = 0.25f * (bfu(row[0]) + bfu(row[3])) + 0.75f * (bfu(row[1]) + bfu(row[2]));
    }
    hs[rm] = s;
  }
  float* op = out + ((size_t)bo << 12);
  const float* npl = noise + ((size_t)b << 12);
#pragma unroll
  for (int pp = 0; pp < 16; pp++) {
    const int P = 16 * qy + pp;
    float s = 0.25f * (hs[pp] + hs[pp + 3]) + 0.75f * (hs[pp + 1] + hs[pp + 2]);
    float v = fmaf(dmv, s, fmaf(nwv, npl[P * 64 + Q], bv));
    v = (v >= 0.f ? v : 0.2f * v) * 1.4142135623730951f;
    op[P * 64 + Q] = v;
  }
}

extern "C" void kernel_launch(void* const* d_in, const int* in_sizes, int n_in,
                              void* d_out, int out_size, void* d_ws, size_t ws_size,
                              hipStream_t stream) {
  const float* x       = (const float*)d_in[0];
  const float* co      = (const float*)d_in[1];
  const float* style   = (const float*)d_in[2];
  const float* noise   = (const float*)d_in[3];
  const float* W       = (const float*)d_in[4];
  const float* mb_w    = (const float*)d_in[5];
  const float* mb_b    = (const float*)d_in[6];
  const float* mod_w   = (const float*)d_in[7];
  const float* mod_b   = (const float*)d_in[8];
  const float* cluster = (const float*)d_in[9];
  const float* gate    = (const float*)d_in[10];
  const float* tmpr    = (const float*)d_in[11];
  const float* nw      = (const float*)d_in[12];
  const float* fb      = (const float*)d_in[13];
  float* out = (float*)d_out;
  char* ws = (char*)d_ws;

  __hip_bfloat16* xs   = (__hip_bfloat16*)(ws + O_XS);
  __hip_bfloat16* out1 = (__hip_bfloat16*)(ws + O_OUT1);
  __hip_bfloat16* wrt  = (__hip_bfloat16*)(ws + O_WRT);
  __hip_bfloat16* wb   = (__hip_bfloat16*)(ws + O_WB);
  float* pgram = (float*)(ws + O_PG);
  float* wsq = (float*)(ws + O_WSQ);
  float* gr  = (float*)(ws + O_GR);
  float* sb  = (float*)(ws + O_SB);
  float* st0 = (float*)(ws + O_ST0);
  float* sts = (float*)(ws + O_STS);
  float* st2 = (float*)(ws + O_ST2);
  float* wni = (float*)(ws + O_WNI);
  float* dm  = (float*)(ws + O_DM);
  float* pacc = pgram;                       // loss partials live in pgram's space
                                             // (consumed by k_mix before k_mfma writes pgram)

  k_big1<<<1101, 256, 0, stream>>>(W, wsq, wni, wrt, (unsigned short*)wb,
                                   style, mod_w, mod_b, st0, co, gate,
                                   cluster, tmpr, mb_w, mb_b, gr, sb, pacc, xs);
  k_mix<<<9, 256, 0, stream>>>(st0, gr, sb, sts, st2, pacc, out + OUT_L);
  k_big2<<<1088, 256, 0, stream>>>(st2, wsq, dm, x, sts, xs);
  k_mfma<<<1188, 256, 0, stream>>>(xs, wrt, out1, wb, pgram);
  k_blur<<<4352, 256, 0, stream>>>(out1, dm, noise, nw, fb, out, pgram, wni, out + OUT_CO);
}

// Round 3
// 241.407 us; speedup vs baseline: 1.3454x; 1.0608x over previous
//
#include <hip/hip_runtime.h>
#include <hip/hip_bf16.h>

#define NB 8
#define LIN_SCALE 0.044194173824159216f
#define SCALE 0.014731391274719736f

typedef __attribute__((ext_vector_type(8))) short short8;
typedef __attribute__((ext_vector_type(4))) float floatx4;

// ---------------- workspace layout (bytes) ----------------
static constexpr size_t O_XS   = 0;                   // 8*34*34*512 bf16 (zero-padded NHWC modulated x)
static constexpr size_t O_OUT1 = 9469952;             // parity planes bf16: 34,611,200
static constexpr size_t O_WRT  = 44081152;            // 9*512*512 bf16 wrt[tap][o][i]
static constexpr size_t O_WB   = 48799744;            // 512*4608 bf16 wb[o][k]
static constexpr size_t O_PG   = 53518336;            // 8*512*512 f32 gram partials
static constexpr size_t O_WSQ  = 61906944;            // 512*512 f32
static constexpr size_t O_CL   = 62955520;            // (unused; layout stability)
static constexpr size_t O_GR   = O_CL + 32768;
static constexpr size_t O_SB   = O_GR + 32768;
static constexpr size_t O_ST0  = O_SB + 1024;
static constexpr size_t O_STS  = O_ST0 + 16384;       // now: pacc (loss partials, 4 KB)
static constexpr size_t O_ST2  = O_STS + 16384;       // unused
static constexpr size_t O_WNI  = O_ST2 + 16384;
static constexpr size_t O_DM   = O_WNI + 2048;
static constexpr size_t O_ACC  = O_DM + 16384;

static constexpr size_t OUT_CO = 16777216;            // d_out offset of co_out (floats)
static constexpr size_t OUT_L  = 17039360;            // d_out offset of losses (floats)

// parity-class tables for the transposed conv (gather form, wf[k]=W[2-k] folded)
__device__ const int c_ylim[4] = {33,33,32,32};
__device__ const int c_xlim[4] = {33,32,33,32};
__device__ const int c_ntap[4] = {4,2,2,1};
__device__ const int c_tap0[4] = {0,4,6,8};
__device__ const int c_nmb[4]  = {69,66,66,64};       // ceil(M/128)
__device__ const int c_cnt[4]  = {276,264,264,256};   // nmb*4
__device__ const int c_dy[9] = {-1,-1,0,0, -1,0, 0,0, 0};
__device__ const int c_dx[9] = {-1,0,-1,0, 0,0, -1,0, 0};
__device__ const int c_ky[9] = {2,2,0,0, 2,0, 1,1, 1};
__device__ const int c_kx[9] = {2,0,2,0, 1,1, 2,0, 1};
__device__ const long c_poff[4] = {0, 4460544, 8785920, 13111296};

__device__ __forceinline__ float wave_red(float v) {
#pragma unroll
  for (int s = 32; s > 0; s >>= 1) v += __shfl_down(v, s);
  return v;
}

__device__ __forceinline__ void gl_lds16(const void* g, void* l) {
  __builtin_amdgcn_global_load_lds((const __attribute__((address_space(1))) void*)g,
                                   (__attribute__((address_space(3))) void*)l, 16, 0, 0);
}

__device__ __forceinline__ unsigned short bf16b(float f) {
  union { __hip_bfloat16 h; unsigned short u; } cv;
  cv.h = __float2bfloat16(f);
  return cv.u;
}

__device__ __forceinline__ float bfu(unsigned short u) {
  union { float f; unsigned u32; } c; c.u32 = ((unsigned)u) << 16; return c.f;
}

// bijective chunked XCD swizzle (m204)
__device__ __forceinline__ int xcd_chunk(int lb, int cnt) {
  const int q = cnt >> 3, r = cnt & 7;
  const int c = lb & 7, i = lb >> 3;
  return (c < r) ? c*(q+1) + i : r*(q+1) + (c - r)*q + i;
}

// ---------------- K1: wproc(512) + st0(64) + losses(512) + prep(1) + xs-border-zero(12) ----------------
__global__ __launch_bounds__(256) void k_big1(const float* __restrict__ W,
    float* __restrict__ wsq, float* __restrict__ wni,
    __hip_bfloat16* __restrict__ wrt, unsigned short* __restrict__ wb,
    const float* __restrict__ style, const float* __restrict__ mod_w,
    const float* __restrict__ mod_b, float* __restrict__ st0,
    const float* __restrict__ co, const float* __restrict__ gate,
    const float* __restrict__ cluster, const float* __restrict__ tmpr,
    const float* __restrict__ mb_w, const float* __restrict__ mb_b,
    float* __restrict__ gr, float* __restrict__ sb,
    float* __restrict__ pacc, __hip_bfloat16* __restrict__ xs) {
  __shared__ float sh[8192];
  __shared__ float extra[8];
  const int bid = blockIdx.x, tid = threadIdx.x;
  const int lane = tid & 63, wv = tid >> 6;
  if (bid < 512) {
    const int o = bid;
    for (int j = tid; j < 4608; j += 256) sh[j] = W[(size_t)o*4608 + j];
    __syncthreads();
    float tot = 0.f;
#pragma unroll
    for (int half = 0; half < 2; half++) {
      const int i = tid + half*256;
      float s = 0.f;
#pragma unroll
      for (int k = 0; k < 9; k++) { float w = sh[i*9 + k]; s = fmaf(w, w, s); }
      wsq[o*512 + i] = s; tot += s;
#pragma unroll
      for (int tp = 0; tp < 9; tp++)
        wrt[((size_t)tp*512 + o)*512 + i] = __float2bfloat16(sh[i*9 + c_ky[tp]*3 + c_kx[tp]]);
    }
    for (int j = tid; j < 4608; j += 256) wb[(size_t)o*4608 + j] = bf16b(sh[j]);
    tot = wave_red(tot);
    if (lane == 0) extra[wv] = tot;
    __syncthreads();
    if (tid == 0) wni[o] = 1.f / fmaxf(sqrtf(extra[0]+extra[1]+extra[2]+extra[3]), 1e-12f);
  } else if (bid < 576) {
    const int b = (bid - 512) >> 3, oc = (bid - 512) & 7;
    sh[tid] = style[b*1024 + 512 + tid];
    sh[tid + 256] = style[b*1024 + 768 + tid];
    __syncthreads();
#pragma unroll
    for (int rr = 0; rr < 16; rr++) {
      const int c = oc*64 + wv*16 + rr;
      const float* mw = mod_w + (size_t)c*512;
      float acc = 0.f;
#pragma unroll
      for (int it = 0; it < 8; it++) acc = fmaf(mw[lane + 64*it], sh[lane + 64*it], acc);
      acc = wave_red(acc);
      if (lane == 0) st0[b*512 + c] = acc*LIN_SCALE + mod_b[c];
    }
  } else if (bid < 1088) {
    // losses: recompute cl locally
    const int i = bid - 576;
    const float tt = 5.f / (1.f + expf(-tmpr[0]));
    const float gg = 1.f / (1.f + expf(-gate[0]));
    for (int j = tid; j < 512; j += 256) {
      float v[16]; float m = -1e30f;
#pragma unroll
      for (int g = 0; g < 16; g++) { v[g] = tt * cluster[g*512 + j]; m = fmaxf(m, v[g]); }
      float s = 0.f;
#pragma unroll
      for (int g = 0; g < 16; g++) { v[g] = expf(v[g] - m); s += v[g]; }
      float inv = 1.f / s;
#pragma unroll
      for (int g = 0; g < 16; g++) sh[g*512 + j] = v[g] * inv;
    }
    __syncthreads();
    float cli[16];
#pragma unroll
    for (int k = 0; k < 16; k++) cli[k] = sh[k*512 + i];
    float p1 = 0.f, p2 = 0.f;
    for (int j = tid; j < 512; j += 256) {
      float d = 0.f;
#pragma unroll
      for (int k = 0; k < 16; k++) d = fmaf(cli[k], sh[k*512 + j], d);
      float S = 1.f / (1.f + expf(-50.f*(co[i*512 + j] - gg)));
      float e = d - S;
      p1 = fmaf(e, e, p1); p2 += S;
    }
    p1 = wave_red(p1); p2 = wave_red(p2);
    if (lane == 0) { extra[wv] = p1; extra[4 + wv] = p2; }
    __syncthreads();
    if (tid == 0)  pacc[i]       = extra[0]+extra[1]+extra[2]+extra[3];
    if (tid == 64) pacc[512 + i] = extra[4]+extra[5]+extra[6]+extra[7];
  } else if (bid == 1088) {
    // prep: gr + sb
    const float tt = 5.f / (1.f + expf(-tmpr[0]));
#pragma unroll
    for (int h = 0; h < 2; h++) {
      const int c = tid + h*256;
      float v[16]; float m = -1e30f;
#pragma unroll
      for (int g = 0; g < 16; g++) { v[g] = tt * cluster[g*512 + c]; m = fmaxf(m, v[g]); }
      float s = 0.f;
#pragma unroll
      for (int g = 0; g < 16; g++) { v[g] = expf(v[g] - m); s += v[g]; }
      float inv = 1.f / s;
      float clv[16]; float m2 = -1e30f;
#pragma unroll
      for (int g = 0; g < 16; g++) { clv[g] = v[g]*inv; m2 = fmaxf(m2, 500.f*clv[g]); }
      float s2 = 0.f; float e2[16];
#pragma unroll
      for (int g = 0; g < 16; g++) { e2[g] = expf(500.f*clv[g] - m2); s2 += e2[g]; }
      float i2 = 1.f / s2;
#pragma unroll
      for (int g = 0; g < 16; g++) gr[g*512 + c] = rintf(e2[g]*i2) + 1e-6f;
    }
    for (int task = wv; task < 128; task += 4) {
      int b = task >> 4, g = task & 15;
      const float* s1 = style + b*1024;
      const float* mw = mb_w + g*512;
      float acc = 0.f;
#pragma unroll
      for (int it = 0; it < 8; it++) acc = fmaf(s1[lane + 64*it], mw[lane + 64*it], acc);
      acc = wave_red(acc);
      if (lane == 0) sb[b*16 + g] = acc*LIN_SCALE + mb_b[g];
    }
  } else {
    // zero the xs border ring (1.08 MB)
    const int id0 = (bid - 1089)*256 + tid;
    const float4 z = make_float4(0.f, 0.f, 0.f, 0.f);
    float4* xq = (float4*)xs;
#pragma unroll
    for (int it = 0; it < 22; ++it) {
      const int id = id0 + it*3072;
      const int c = id & 63;
      const int pb = id >> 6;
      const int b = pb / 132;
      const int pix = pb - b*132;
      int y, xx;
      if (pix < 34)       { y = 0;        xx = pix; }
      else if (pix < 68)  { y = 33;       xx = pix - 34; }
      else if (pix < 100) { y = pix - 67; xx = 0; }
      else                { y = pix - 99; xx = 33; }
      xq[((size_t)(b*34 + y)*34 + xx)*64 + c] = z;
    }
  }
}

// ---------------- K2: demod(64) + xsprep(1024) + loss-reduce(1); style-mix recomputed inline ----------------
__global__ __launch_bounds__(256) void k_big2(const float* __restrict__ st0,
    const float* __restrict__ gr, const float* __restrict__ sb,
    const float* __restrict__ wsq, float* __restrict__ dm,
    const float* __restrict__ x, __hip_bfloat16* __restrict__ xs,
    const float* __restrict__ pacc, float* __restrict__ out_tail) {
  __shared__ float L[64*65];
  __shared__ float red[16][4];
  __shared__ float inv[16];
  __shared__ float sbb[16];
  const int tid = threadIdx.x;
  const int lane = tid & 63, wv = tid >> 6;

  if (blockIdx.x == 1088) {
    // loss-partial reduce (old k_mix block 8)
    float a = pacc[tid] + pacc[tid + 256];
    float b2 = pacc[512 + tid] + pacc[768 + tid];
    a = wave_red(a); b2 = wave_red(b2);
    if (lane == 0) { red[0][wv] = a; red[1][wv] = b2; }
    __syncthreads();
    if (tid == 0) {
      float p1 = red[0][0]+red[0][1]+red[0][2]+red[0][3];
      float p2 = red[1][0]+red[1][1]+red[1][2]+red[1][3];
      out_tail[0] = p1;
      float d = 16384.f - p2;
      out_tail[1] = d*d;
    }
    return;
  }

  // ---- inline style-mix (k_mix body) for this block's batch b ----
  const int b = (blockIdx.x < 64) ? (blockIdx.x >> 3) : ((blockIdx.x - 64) >> 7);
  float s0 = st0[b*512 + tid], s1 = st0[b*512 + 256 + tid];
  float g0[16], g1[16];
#pragma unroll
  for (int g = 0; g < 16; g++) { g0[g] = gr[g*512 + tid]; g1[g] = gr[g*512 + 256 + tid]; }
#pragma unroll
  for (int g = 0; g < 16; g++) {
    float a = g0[g]*s0, c = g1[g]*s1;
    float p = wave_red(a*a + c*c);
    if (lane == 0) red[g][wv] = p;
  }
  if (tid < 16) sbb[tid] = sb[b*16 + tid];
  __syncthreads();
  if (tid < 16) {
    float ttn = red[tid][0] + red[tid][1] + red[tid][2] + red[tid][3];
    inv[tid] = 1.f / fmaxf(sqrtf(ttn), 1e-12f);
  }
  __syncthreads();
  float f0 = 0.f, f1 = 0.f;
#pragma unroll
  for (int g = 0; g < 16; g++) {
    float w = inv[g]*sbb[g];
    f0 = fmaf(g0[g], w, f0); f1 = fmaf(g1[g], w, f1);
  }
  const float sn0 = s0*f0, sn1 = s1*f1;

  if (blockIdx.x < 64) {
    // demod: st2 = sn^2 into L, then rowwise wsq dot
    const int oc = blockIdx.x & 7;
    L[tid] = sn0*sn0;
    L[tid + 256] = sn1*sn1;
    __syncthreads();
#pragma unroll
    for (int rr = 0; rr < 16; rr++) {
      const int o = oc*64 + wv*16 + rr;
      const float* wp = wsq + (size_t)o*512;
      float acc = 0.f;
#pragma unroll
      for (int it = 0; it < 8; it++) acc = fmaf(wp[lane + 64*it], L[lane + 64*it], acc);
      acc = wave_red(acc);
      if (lane == 0) dm[b*512 + o] = rsqrtf((1.0f/4608.0f)*acc + 1e-8f);
    }
    return;
  }

  // xsprep: sts = sn*SCALE, broadcast via L, then modulate+transpose x
  L[tid] = sn0*SCALE;
  L[tid + 256] = sn1*SCALE;
  __syncthreads();
  const int id = blockIdx.x - 64;
  const int p0 = ((id >> 3) & 15) * 64;
  const int i0 = (id & 7) * 64;
  const int iw = tid & 63, pw = tid >> 6;
  const float sv = L[i0 + iw];
  __syncthreads();
  const int lp = tid & 63, li = tid >> 6;
  const float* xp = x + ((size_t)b*512 + i0)*1024 + p0;
#pragma unroll
  for (int ii = 0; ii < 16; ii++) {
    const int i = li + 4*ii;
    L[i*65 + lp] = xp[(size_t)i*1024 + lp];
  }
  __syncthreads();
#pragma unroll
  for (int pp = 0; pp < 16; pp++) {
    const int pix = p0 + pw + 4*pp;
    const int y = pix >> 5, xq = pix & 31;
    xs[(((size_t)b*34 + (y+1))*34 + (xq+1))*512 + i0 + iw] = __float2bfloat16(L[iw*65 + pw + 4*pp] * sv);
  }
}

// ---------------- K3: conv MFMA (1060) + gram MFMA (128), 1188 blocks ----------------
// Double-buffered LDS (2 x {A[128][32] | B[128][32]} bf16 = 32 KB), counted vmcnt(4):
// step s+1's 4 global_load_lds stay IN FLIGHT across the barrier and under step s's
// MFMA (T3/T4 pattern). vmcnt+barrier fused in one asm so nothing slips between.
// Source-side XOR swizzle retained from round 2 (neutral but verified).
__global__ __launch_bounds__(256, 4) void k_mfma(
    const __hip_bfloat16* __restrict__ xs, const __hip_bfloat16* __restrict__ wrt,
    __hip_bfloat16* __restrict__ out1, const __hip_bfloat16* __restrict__ wb,
    float* __restrict__ pgram) {
  __shared__ __hip_bfloat16 smem[16384];
  const int fid = blockIdx.x;
  const int tid = threadIdx.x;
  const int lane = tid & 63, wv = tid >> 6;
  const int wm = (wv >> 1) << 6, wn = (wv & 1) << 6;
  const int col16 = lane & 15, quad = lane >> 4;
  const int colp = col16 ^ ((col16 >> 2) & 1);
  const int soff = (quad ^ (col16 & 3)) << 3;

  int aoff[4], boff[4];
#pragma unroll
  for (int t = 0; t < 4; t++) {
    aoff[t] = (wm + t*16 + colp)*32 + soff;
    boff[t] = 4096 + (wn + t*16 + colp)*32 + soff;
  }
  floatx4 acc[4][4];
#pragma unroll
  for (int i = 0; i < 4; i++)
#pragma unroll
    for (int j = 0; j < 4; j++) acc[i][j] = (floatx4){0.f, 0.f, 0.f, 0.f};

  if (fid >= 276 && fid < 404) {
    // ---- gram ----
    const int g = xcd_chunk(fid - 276, 128);
    const int m0 = (g & 3) * 128, n0 = ((g >> 2) & 3) * 128;
    const long kz = (long)(g >> 4) * 576;
    long abase[2], bbase[2]; int ldso[2];
#pragma unroll
    for (int r = 0; r < 2; r++) {
      const int idx = r*256 + tid;
      const int rowp = idx >> 2;
      const int row = rowp ^ ((rowp >> 2) & 1);
      const int kc = (((idx & 3) ^ (row & 3)) << 3);
      abase[r] = (long)(m0 + row)*4608 + kz + kc;
      bbase[r] = (long)(n0 + row)*4608 + kz + kc;
      ldso[r] = idx << 3;
    }
#define STAGE_GRAM(s_) do { \
      const int kk_ = (s_) << 5; \
      const int lo_ = ((s_) & 1) << 13; \
      gl_lds16(wb + (abase[0] + kk_), smem + lo_ + ldso[0]); \
      gl_lds16(wb + (abase[1] + kk_), smem + lo_ + ldso[1]); \
      gl_lds16(wb + (bbase[0] + kk_), smem + lo_ + 4096 + ldso[0]); \
      gl_lds16(wb + (bbase[1] + kk_), smem + lo_ + 4096 + ldso[1]); \
    } while (0)
    STAGE_GRAM(0);
    for (int s = 0; s < 18; ++s) {
      if (s + 1 < 18) {
        STAGE_GRAM(s + 1);
        asm volatile("s_waitcnt vmcnt(4)\n\ts_barrier" ::: "memory");
      } else {
        asm volatile("s_waitcnt vmcnt(0)\n\ts_barrier" ::: "memory");
      }
      const int lo = (s & 1) << 13;
      short8 af[4], bfr[4];
#pragma unroll
      for (int t = 0; t < 4; t++) {
        af[t]  = *(const short8*)(smem + lo + aoff[t]);
        bfr[t] = *(const short8*)(smem + lo + boff[t]);
      }
#pragma unroll
      for (int i = 0; i < 4; i++)
#pragma unroll
        for (int j = 0; j < 4; j++)
          acc[i][j] = __builtin_amdgcn_mfma_f32_16x16x32_bf16(af[i], bfr[j], acc[i][j], 0, 0, 0);
      asm volatile("s_barrier" ::: "memory");
    }
    float* pg = pgram + (size_t)(g >> 4) * 262144;
#pragma unroll
    for (int i = 0; i < 4; i++)
#pragma unroll
      for (int j = 0; j < 4; j++) {
        const int m = m0 + wm + i*16 + (quad << 2);
        const int n = n0 + wn + j*16 + col16;
#pragma unroll
        for (int r = 0; r < 4; r++) pg[(size_t)(m + r)*512 + n] = acc[i][j][r];
      }
    return;
  }

  // ---- conv ----
  int cls, lb;
  if (fid < 276)      { cls = 0; lb = fid; }
  else if (fid < 668) { cls = 1; lb = fid - 404; }
  else if (fid < 932) { cls = 2; lb = fid - 668; }
  else                { cls = 3; lb = fid - 932; }
  const int lg = xcd_chunk(lb, c_cnt[cls]);
  const int mb = lg >> 2, nb = lg & 3;
  const int xlim = c_xlim[cls];
  const int npix = c_ylim[cls] * xlim;
  const int M = NB * npix;
  const int m0 = mb * 128, n0 = nb * 128;
  const int t0 = c_tap0[cls];
  const int ntap = c_ntap[cls];

  long abase[2], bbase[2]; int ldso[2];
#pragma unroll
  for (int r = 0; r < 2; r++) {
    const int idx = r*256 + tid;
    const int rowp = idx >> 2;
    const int row = rowp ^ ((rowp >> 2) & 1);
    const int kc = (((idx & 3) ^ (row & 3)) << 3);
    int rm = m0 + row; if (rm >= M) rm = 0;
    const int b = rm / npix; const int rem = rm - b*npix;
    const int yy = rem / xlim; const int xx = rem - yy*xlim;
    abase[r] = ((long)(b*34 + yy + 1)*34 + (xx + 1))*512 + kc;
    bbase[r] = ((long)(t0*512 + n0 + row))*512 + kc;
    ldso[r] = idx << 3;
  }

  const int nst = ntap << 4;
#define STAGE_CONV(s_) do { \
    const int tap_ = t0 + ((s_) >> 4); \
    const long adel_ = (long)((c_dy[tap_]*34 + c_dx[tap_])*512); \
    const long bdel_ = (long)((s_) >> 4) << 18; \
    const int kk_ = ((s_) & 15) << 5; \
    const int lo_ = ((s_) & 1) << 13; \
    gl_lds16(xs + (abase[0] + adel_ + kk_), smem + lo_ + ldso[0]); \
    gl_lds16(xs + (abase[1] + adel_ + kk_), smem + lo_ + ldso[1]); \
    gl_lds16(wrt + (bbase[0] + bdel_ + kk_), smem + lo_ + 4096 + ldso[0]); \
    gl_lds16(wrt + (bbase[1] + bdel_ + kk_), smem + lo_ + 4096 + ldso[1]); \
  } while (0)
  STAGE_CONV(0);
  for (int s = 0; s < nst; ++s) {
    if (s + 1 < nst) {
      STAGE_CONV(s + 1);
      asm volatile("s_waitcnt vmcnt(4)\n\ts_barrier" ::: "memory");
    } else {
      asm volatile("s_waitcnt vmcnt(0)\n\ts_barrier" ::: "memory");
    }
    const int lo = (s & 1) << 13;
    short8 af[4], bfr[4];
#pragma unroll
    for (int t = 0; t < 4; t++) {
      af[t]  = *(const short8*)(smem + lo + aoff[t]);
      bfr[t] = *(const short8*)(smem + lo + boff[t]);
    }
#pragma unroll
    for (int i = 0; i < 4; i++)
#pragma unroll
      for (int j = 0; j < 4; j++)
        acc[i][j] = __builtin_amdgcn_mfma_f32_16x16x32_bf16(af[i], bfr[j], acc[i][j], 0, 0, 0);
    asm volatile("s_barrier" ::: "memory");
  }

  // two-pass epilogue: transpose 64 n-cols at a time through Ct[64][136]
  __hip_bfloat16* plane = out1 + c_poff[cls];
#pragma unroll
  for (int h = 0; h < 2; h++) {
    if ((wv & 1) == h) {
#pragma unroll
      for (int i = 0; i < 4; i++) {
        const int mrow = wm + i*16 + (quad << 2);
#pragma unroll
        for (int j = 0; j < 4; j++) {
          const int ncl = j*16 + col16;
          ushort4 v;
          v.x = bf16b(acc[i][j][0]); v.y = bf16b(acc[i][j][1]);
          v.z = bf16b(acc[i][j][2]); v.w = bf16b(acc[i][j][3]);
          *(ushort4*)(smem + ncl*136 + mrow) = v;
        }
      }
    }
    __syncthreads();
#pragma unroll
    for (int it = 0; it < 4; it++) {
      const int c = it*256 + tid;
      const int ol = c >> 4, ml = (c & 15) << 3;
      const int mg = m0 + ml;
      if (mg < M) {
        const ushort4 v = *(const ushort4*)(smem + ol*136 + ml);
        *(ushort4*)(plane + (long)(n0 + h*64 + ol)*M + mg) = v;
      }
    }
    __syncthreads();
  }
}

// ---------------- K4: gram reduce+normalize (256) + blur+epilogue (4096) ----------------
__global__ __launch_bounds__(256) void k_blur(const __hip_bfloat16* __restrict__ out1,
    const float* __restrict__ dm, const float* __restrict__ noise,
    const float* __restrict__ nw, const float* __restrict__ fb, float* __restrict__ out,
    const float* __restrict__ pgram, const float* __restrict__ wni,
    float* __restrict__ co_out) {
  if (blockIdx.x < 256) {
    const int i4 = blockIdx.x*256 + threadIdx.x;
    float4 s = make_float4(0.f, 0.f, 0.f, 0.f);
#pragma unroll
    for (int z = 0; z < 8; z++) {
      const float4 v = ((const float4*)(pgram + (size_t)z*262144))[i4];
      s.x += v.x; s.y += v.y; s.z += v.z; s.w += v.w;
    }
    const float wm = wni[i4 >> 7];
    const float4 wn4 = ((const float4*)wni)[i4 & 127];
    float4 o;
    o.x = s.x*wm*wn4.x; o.y = s.y*wm*wn4.y; o.z = s.z*wm*wn4.z; o.w = s.w*wm*wn4.w;
    ((float4*)co_out)[i4] = o;
    return;
  }
  const int bo = blockIdx.x - 256;
  const int b = bo >> 9, o = bo & 511;
  __shared__ unsigned short L[65 * 68];
  const int tid = threadIdx.x;
  const unsigned short* p0 = (const unsigned short*)out1 + 0        + (long)o * 8712 + b * 1089;
  const unsigned short* p1 = (const unsigned short*)out1 + 4460544  + (long)o * 8448 + b * 1056;
  const unsigned short* p2 = (const unsigned short*)out1 + 8785920  + (long)o * 8448 + b * 1056;
  const unsigned short* p3 = (const unsigned short*)out1 + 13111296 + (long)o * 8192 + b * 1024;
  for (int m = tid; m < 65; m += 256) { L[m*68 + 0] = 0; L[m*68 + 66] = 0; }
  for (int e = tid; e < 1089; e += 256) { int y = e / 33, x = e - 33*y; L[(2*y)*68 + 2*x + 1] = p0[e]; }
  for (int e = tid; e < 1056; e += 256) { int y = e >> 5, x = e & 31;   L[(2*y)*68 + 2*x + 2] = p1[e]; }
  for (int e = tid; e < 1056; e += 256) { int y = e / 33, x = e - 33*y; L[(2*y+1)*68 + 2*x + 1] = p2[e]; }
  for (int e = tid; e < 1024; e += 256) { int y = e >> 5, x = e & 31;   L[(2*y+1)*68 + 2*x + 2] = p3[e]; }
  __syncthreads();
  const float dmv = dm[bo];
  const float nwv = nw[0];
  const float bv = fb[o];
  const int Q = tid & 63;
  const int qy = tid >> 6;
  const int mbase = 16 * qy - 1;
  float hs[18];
#pragma unroll
  for (int rm = 0; rm < 18; rm++) {
    const int m = mbase + rm;
    float s = 0.f;
    if (m >= 0 && m <= 64) {
      const unsigned short* row = L + m*68 + Q;
      s = 0.25f * (bfu(row[0]) + bfu(row[3])) + 0.75f * (bfu(row[1]) + bfu(row[2]));
    }
    hs[rm] = s;
  }
  float* op = out + ((size_t)bo << 12);
  const float* npl = noise + ((size_t)b << 12);
#pragma unroll
  for (int pp = 0; pp < 16; pp++) {
    const int P = 16 * qy + pp;
    float s = 0.25f * (hs[pp] + hs[pp + 3]) + 0.75f * (hs[pp + 1] + hs[pp + 2]);
    float v = fmaf(dmv, s, fmaf(nwv, npl[P * 64 + Q], bv));
    v = (v >= 0.f ? v : 0.2f * v) * 1.4142135623730951f;
    op[P * 64 + Q] = v;
  }
}

extern "C" void kernel_launch(void* const* d_in, const int* in_sizes, int n_in,
                              void* d_out, int out_size, void* d_ws, size_t ws_size,
                              hipStream_t stream) {
  const float* x       = (const float*)d_in[0];
  const float* co      = (const float*)d_in[1];
  const float* style   = (const float*)d_in[2];
  const float* noise   = (const float*)d_in[3];
  const float* W       = (const float*)d_in[4];
  const float* mb_w    = (const float*)d_in[5];
  const float* mb_b    = (const float*)d_in[6];
  const float* mod_w   = (const float*)d_in[7];
  const float* mod_b   = (const float*)d_in[8];
  const float* cluster = (const float*)d_in[9];
  const float* gate    = (const float*)d_in[10];
  const float* tmpr    = (const float*)d_in[11];
  const float* nw      = (const float*)d_in[12];
  const float* fb      = (const float*)d_in[13];
  float* out = (float*)d_out;
  char* ws = (char*)d_ws;

  __hip_bfloat16* xs   = (__hip_bfloat16*)(ws + O_XS);
  __hip_bfloat16* out1 = (__hip_bfloat16*)(ws + O_OUT1);
  __hip_bfloat16* wrt  = (__hip_bfloat16*)(ws + O_WRT);
  __hip_bfloat16* wb   = (__hip_bfloat16*)(ws + O_WB);
  float* pgram = (float*)(ws + O_PG);
  float* wsq = (float*)(ws + O_WSQ);
  float* gr  = (float*)(ws + O_GR);
  float* sb  = (float*)(ws + O_SB);
  float* st0 = (float*)(ws + O_ST0);
  float* wni = (float*)(ws + O_WNI);
  float* dm  = (float*)(ws + O_DM);
  float* pacc = (float*)(ws + O_STS);        // loss partials (sts slot is free now)

  k_big1<<<1101, 256, 0, stream>>>(W, wsq, wni, wrt, (unsigned short*)wb,
                                   style, mod_w, mod_b, st0, co, gate,
                                   cluster, tmpr, mb_w, mb_b, gr, sb, pacc, xs);
  k_big2<<<1089, 256, 0, stream>>>(st0, gr, sb, wsq, dm, x, xs, pacc, out + OUT_L);
  k_mfma<<<1188, 256, 0, stream>>>(xs, wrt, out1, wb, pgram);
  k_blur<<<4352, 256, 0, stream>>>(out1, dm, noise, nw, fb, out, pgram, wni, out + OUT_CO);
}

// Round 4
// 240.383 us; speedup vs baseline: 1.3511x; 1.0043x over previous
//
#include <hip/hip_runtime.h>
#include <hip/hip_bf16.h>

#define NB 8
#define LIN_SCALE 0.044194173824159216f
#define SCALE 0.014731391274719736f

typedef __attribute__((ext_vector_type(8))) short short8;
typedef __attribute__((ext_vector_type(4))) float floatx4;

// ---------------- workspace layout (bytes) ----------------
static constexpr size_t O_XS   = 0;                   // 8*34*34*512 bf16 (zero-padded NHWC modulated x)
static constexpr size_t O_OUT1 = 9469952;             // parity planes bf16: 34,611,200
static constexpr size_t O_WRT  = 44081152;            // 9*512*512 bf16 wrt[tap][o][i]
static constexpr size_t O_WB   = 48799744;            // 512*4608 bf16 wb[o][k]
static constexpr size_t O_PG   = 53518336;            // 8*512*512 f32 gram partials
static constexpr size_t O_WSQ  = 61906944;            // 512*512 f32
static constexpr size_t O_CL   = 62955520;            // (unused; layout stability)
static constexpr size_t O_GR   = O_CL + 32768;
static constexpr size_t O_SB   = O_GR + 32768;
static constexpr size_t O_ST0  = O_SB + 1024;
static constexpr size_t O_STS  = O_ST0 + 16384;       // pacc (loss partials, 4 KB)
static constexpr size_t O_ST2  = O_STS + 16384;       // unused
static constexpr size_t O_WNI  = O_ST2 + 16384;
static constexpr size_t O_DM   = O_WNI + 2048;
static constexpr size_t O_ACC  = O_DM + 16384;

static constexpr size_t OUT_CO = 16777216;            // d_out offset of co_out (floats)
static constexpr size_t OUT_L  = 17039360;            // d_out offset of losses (floats)

// parity-class tables for the transposed conv (gather form, wf[k]=W[2-k] folded)
__device__ const int c_ylim[4] = {33,33,32,32};
__device__ const int c_xlim[4] = {33,32,33,32};
__device__ const int c_ntap[4] = {4,2,2,1};
__device__ const int c_tap0[4] = {0,4,6,8};
__device__ const int c_nmb[4]  = {69,66,66,64};       // ceil(M/128)
__device__ const int c_cnt[4]  = {276,264,264,256};   // nmb*4
__device__ const int c_dy[9] = {-1,-1,0,0, -1,0, 0,0, 0};
__device__ const int c_dx[9] = {-1,0,-1,0, 0,0, -1,0, 0};
__device__ const int c_ky[9] = {2,2,0,0, 2,0, 1,1, 1};
__device__ const int c_kx[9] = {2,0,2,0, 1,1, 2,0, 1};
__device__ const long c_poff[4] = {0, 4460544, 8785920, 13111296};

__device__ __forceinline__ float wave_red(float v) {
#pragma unroll
  for (int s = 32; s > 0; s >>= 1) v += __shfl_down(v, s);
  return v;
}

__device__ __forceinline__ void gl_lds16(const void* g, void* l) {
  __builtin_amdgcn_global_load_lds((const __attribute__((address_space(1))) void*)g,
                                   (__attribute__((address_space(3))) void*)l, 16, 0, 0);
}

__device__ __forceinline__ unsigned short bf16b(float f) {
  union { __hip_bfloat16 h; unsigned short u; } cv;
  cv.h = __float2bfloat16(f);
  return cv.u;
}

__device__ __forceinline__ float bfu(unsigned short u) {
  union { float f; unsigned u32; } c; c.u32 = ((unsigned)u) << 16; return c.f;
}

// bijective chunked XCD swizzle (m204)
__device__ __forceinline__ int xcd_chunk(int lb, int cnt) {
  const int q = cnt >> 3, r = cnt & 7;
  const int c = lb & 7, i = lb >> 3;
  return (c < r) ? c*(q+1) + i : r*(q+1) + (c - r)*q + i;
}

// ---------------- K1: wproc(512) + st0(64) + losses(512) + prep(1) + xs-border-zero(12) ----------------
__global__ __launch_bounds__(256) void k_big1(const float* __restrict__ W,
    float* __restrict__ wsq, float* __restrict__ wni,
    __hip_bfloat16* __restrict__ wrt, unsigned short* __restrict__ wb,
    const float* __restrict__ style, const float* __restrict__ mod_w,
    const float* __restrict__ mod_b, float* __restrict__ st0,
    const float* __restrict__ co, const float* __restrict__ gate,
    const float* __restrict__ cluster, const float* __restrict__ tmpr,
    const float* __restrict__ mb_w, const float* __restrict__ mb_b,
    float* __restrict__ gr, float* __restrict__ sb,
    float* __restrict__ pacc, __hip_bfloat16* __restrict__ xs) {
  __shared__ float sh[8192];
  __shared__ float extra[8];
  const int bid = blockIdx.x, tid = threadIdx.x;
  const int lane = tid & 63, wv = tid >> 6;
  if (bid < 512) {
    const int o = bid;
    for (int j = tid; j < 4608; j += 256) sh[j] = W[(size_t)o*4608 + j];
    __syncthreads();
    float tot = 0.f;
#pragma unroll
    for (int half = 0; half < 2; half++) {
      const int i = tid + half*256;
      float s = 0.f;
#pragma unroll
      for (int k = 0; k < 9; k++) { float w = sh[i*9 + k]; s = fmaf(w, w, s); }
      wsq[o*512 + i] = s; tot += s;
#pragma unroll
      for (int tp = 0; tp < 9; tp++)
        wrt[((size_t)tp*512 + o)*512 + i] = __float2bfloat16(sh[i*9 + c_ky[tp]*3 + c_kx[tp]]);
    }
    for (int j = tid; j < 4608; j += 256) wb[(size_t)o*4608 + j] = bf16b(sh[j]);
    tot = wave_red(tot);
    if (lane == 0) extra[wv] = tot;
    __syncthreads();
    if (tid == 0) wni[o] = 1.f / fmaxf(sqrtf(extra[0]+extra[1]+extra[2]+extra[3]), 1e-12f);
  } else if (bid < 576) {
    const int b = (bid - 512) >> 3, oc = (bid - 512) & 7;
    sh[tid] = style[b*1024 + 512 + tid];
    sh[tid + 256] = style[b*1024 + 768 + tid];
    __syncthreads();
#pragma unroll
    for (int rr = 0; rr < 16; rr++) {
      const int c = oc*64 + wv*16 + rr;
      const float* mw = mod_w + (size_t)c*512;
      float acc = 0.f;
#pragma unroll
      for (int it = 0; it < 8; it++) acc = fmaf(mw[lane + 64*it], sh[lane + 64*it], acc);
      acc = wave_red(acc);
      if (lane == 0) st0[b*512 + c] = acc*LIN_SCALE + mod_b[c];
    }
  } else if (bid < 1088) {
    // losses: recompute cl locally
    const int i = bid - 576;
    const float tt = 5.f / (1.f + expf(-tmpr[0]));
    const float gg = 1.f / (1.f + expf(-gate[0]));
    for (int j = tid; j < 512; j += 256) {
      float v[16]; float m = -1e30f;
#pragma unroll
      for (int g = 0; g < 16; g++) { v[g] = tt * cluster[g*512 + j]; m = fmaxf(m, v[g]); }
      float s = 0.f;
#pragma unroll
      for (int g = 0; g < 16; g++) { v[g] = expf(v[g] - m); s += v[g]; }
      float inv = 1.f / s;
#pragma unroll
      for (int g = 0; g < 16; g++) sh[g*512 + j] = v[g] * inv;
    }
    __syncthreads();
    float cli[16];
#pragma unroll
    for (int k = 0; k < 16; k++) cli[k] = sh[k*512 + i];
    float p1 = 0.f, p2 = 0.f;
    for (int j = tid; j < 512; j += 256) {
      float d = 0.f;
#pragma unroll
      for (int k = 0; k < 16; k++) d = fmaf(cli[k], sh[k*512 + j], d);
      float S = 1.f / (1.f + expf(-50.f*(co[i*512 + j] - gg)));
      float e = d - S;
      p1 = fmaf(e, e, p1); p2 += S;
    }
    p1 = wave_red(p1); p2 = wave_red(p2);
    if (lane == 0) { extra[wv] = p1; extra[4 + wv] = p2; }
    __syncthreads();
    if (tid == 0)  pacc[i]       = extra[0]+extra[1]+extra[2]+extra[3];
    if (tid == 64) pacc[512 + i] = extra[4]+extra[5]+extra[6]+extra[7];
  } else if (bid == 1088) {
    // prep: gr + sb
    const float tt = 5.f / (1.f + expf(-tmpr[0]));
#pragma unroll
    for (int h = 0; h < 2; h++) {
      const int c = tid + h*256;
      float v[16]; float m = -1e30f;
#pragma unroll
      for (int g = 0; g < 16; g++) { v[g] = tt * cluster[g*512 + c]; m = fmaxf(m, v[g]); }
      float s = 0.f;
#pragma unroll
      for (int g = 0; g < 16; g++) { v[g] = expf(v[g] - m); s += v[g]; }
      float inv = 1.f / s;
      float clv[16]; float m2 = -1e30f;
#pragma unroll
      for (int g = 0; g < 16; g++) { clv[g] = v[g]*inv; m2 = fmaxf(m2, 500.f*clv[g]); }
      float s2 = 0.f; float e2[16];
#pragma unroll
      for (int g = 0; g < 16; g++) { e2[g] = expf(500.f*clv[g] - m2); s2 += e2[g]; }
      float i2 = 1.f / s2;
#pragma unroll
      for (int g = 0; g < 16; g++) gr[g*512 + c] = rintf(e2[g]*i2) + 1e-6f;
    }
    for (int task = wv; task < 128; task += 4) {
      int b = task >> 4, g = task & 15;
      const float* s1 = style + b*1024;
      const float* mw = mb_w + g*512;
      float acc = 0.f;
#pragma unroll
      for (int it = 0; it < 8; it++) acc = fmaf(s1[lane + 64*it], mw[lane + 64*it], acc);
      acc = wave_red(acc);
      if (lane == 0) sb[b*16 + g] = acc*LIN_SCALE + mb_b[g];
    }
  } else {
    // zero the xs border ring (1.08 MB)
    const int id0 = (bid - 1089)*256 + tid;
    const float4 z = make_float4(0.f, 0.f, 0.f, 0.f);
    float4* xq = (float4*)xs;
#pragma unroll
    for (int it = 0; it < 22; ++it) {
      const int id = id0 + it*3072;
      const int c = id & 63;
      const int pb = id >> 6;
      const int b = pb / 132;
      const int pix = pb - b*132;
      int y, xx;
      if (pix < 34)       { y = 0;        xx = pix; }
      else if (pix < 68)  { y = 33;       xx = pix - 34; }
      else if (pix < 100) { y = pix - 67; xx = 0; }
      else                { y = pix - 99; xx = 33; }
      xq[((size_t)(b*34 + y)*34 + xx)*64 + c] = z;
    }
  }
}

// ---------------- K2: demod(64) + xsprep(1024) + loss-reduce(1); style-mix inline ----------------
__global__ __launch_bounds__(256) void k_big2(const float* __restrict__ st0,
    const float* __restrict__ gr, const float* __restrict__ sb,
    const float* __restrict__ wsq, float* __restrict__ dm,
    const float* __restrict__ x, __hip_bfloat16* __restrict__ xs,
    const float* __restrict__ pacc, float* __restrict__ out_tail) {
  __shared__ float L[64*65];
  __shared__ float red[16][4];
  __shared__ float inv[16];
  __shared__ float sbb[16];
  const int tid = threadIdx.x;
  const int lane = tid & 63, wv = tid >> 6;

  if (blockIdx.x == 1088) {
    float a = pacc[tid] + pacc[tid + 256];
    float b2 = pacc[512 + tid] + pacc[768 + tid];
    a = wave_red(a); b2 = wave_red(b2);
    if (lane == 0) { red[0][wv] = a; red[1][wv] = b2; }
    __syncthreads();
    if (tid == 0) {
      float p1 = red[0][0]+red[0][1]+red[0][2]+red[0][3];
      float p2 = red[1][0]+red[1][1]+red[1][2]+red[1][3];
      out_tail[0] = p1;
      float d = 16384.f - p2;
      out_tail[1] = d*d;
    }
    return;
  }

  const int b = (blockIdx.x < 64) ? (blockIdx.x >> 3) : ((blockIdx.x - 64) >> 7);
  float s0 = st0[b*512 + tid], s1 = st0[b*512 + 256 + tid];
  float g0[16], g1[16];
#pragma unroll
  for (int g = 0; g < 16; g++) { g0[g] = gr[g*512 + tid]; g1[g] = gr[g*512 + 256 + tid]; }
#pragma unroll
  for (int g = 0; g < 16; g++) {
    float a = g0[g]*s0, c = g1[g]*s1;
    float p = wave_red(a*a + c*c);
    if (lane == 0) red[g][wv] = p;
  }
  if (tid < 16) sbb[tid] = sb[b*16 + tid];
  __syncthreads();
  if (tid < 16) {
    float ttn = red[tid][0] + red[tid][1] + red[tid][2] + red[tid][3];
    inv[tid] = 1.f / fmaxf(sqrtf(ttn), 1e-12f);
  }
  __syncthreads();
  float f0 = 0.f, f1 = 0.f;
#pragma unroll
  for (int g = 0; g < 16; g++) {
    float w = inv[g]*sbb[g];
    f0 = fmaf(g0[g], w, f0); f1 = fmaf(g1[g], w, f1);
  }
  const float sn0 = s0*f0, sn1 = s1*f1;

  if (blockIdx.x < 64) {
    const int oc = blockIdx.x & 7;
    L[tid] = sn0*sn0;
    L[tid + 256] = sn1*sn1;
    __syncthreads();
#pragma unroll
    for (int rr = 0; rr < 16; rr++) {
      const int o = oc*64 + wv*16 + rr;
      const float* wp = wsq + (size_t)o*512;
      float acc = 0.f;
#pragma unroll
      for (int it = 0; it < 8; it++) acc = fmaf(wp[lane + 64*it], L[lane + 64*it], acc);
      acc = wave_red(acc);
      if (lane == 0) dm[b*512 + o] = rsqrtf((1.0f/4608.0f)*acc + 1e-8f);
    }
    return;
  }

  L[tid] = sn0*SCALE;
  L[tid + 256] = sn1*SCALE;
  __syncthreads();
  const int id = blockIdx.x - 64;
  const int p0 = ((id >> 3) & 15) * 64;
  const int i0 = (id & 7) * 64;
  const int iw = tid & 63, pw = tid >> 6;
  const float sv = L[i0 + iw];
  __syncthreads();
  const int lp = tid & 63, li = tid >> 6;
  const float* xp = x + ((size_t)b*512 + i0)*1024 + p0;
#pragma unroll
  for (int ii = 0; ii < 16; ii++) {
    const int i = li + 4*ii;
    L[i*65 + lp] = xp[(size_t)i*1024 + lp];
  }
  __syncthreads();
#pragma unroll
  for (int pp = 0; pp < 16; pp++) {
    const int pix = p0 + pw + 4*pp;
    const int y = pix >> 5, xq = pix & 31;
    xs[(((size_t)b*34 + (y+1))*34 + (xq+1))*512 + i0 + iw] = __float2bfloat16(L[iw*65 + pw + 4*pp] * sv);
  }
}

// ---------------- K3: conv MFMA (1060) + gram MFMA (128), 1188 blocks ----------------
// Triple-buffered LDS (3 x {A[128][32] | B[128][32]} bf16 = 48 KB), SINGLE barrier/step:
//   iter s: vmcnt(4)[own loads(s)] -> s_barrier -> STAGE(s+2)->buf[(s+2)%3]
//           -> ds_read buf[s%3] -> MFMA
// Race-free: all waves vmcnt before the barrier => buf[s%3] complete for everyone;
// STAGE(s+2) overwrites a buffer last read at step s-1, whose reads finished
// (lgkmcnt before MFMA(s-1)) before each wave reached barrier(s). Loads get ~2
// full steps to land. Epilogue Ct stride 136->138 (69 dwords, odd) to kill the
// 4-aligned-bank epilogue conflicts (the constant 5.58M SQ_LDS_BANK_CONFLICT).
__global__ __launch_bounds__(256, 3) void k_mfma(
    const __hip_bfloat16* __restrict__ xs, const __hip_bfloat16* __restrict__ wrt,
    __hip_bfloat16* __restrict__ out1, const __hip_bfloat16* __restrict__ wb,
    float* __restrict__ pgram) {
  __shared__ __hip_bfloat16 smem[24576];
  const int fid = blockIdx.x;
  const int tid = threadIdx.x;
  const int lane = tid & 63, wv = tid >> 6;
  const int wm = (wv >> 1) << 6, wn = (wv & 1) << 6;
  const int col16 = lane & 15, quad = lane >> 4;
  const int colp = col16 ^ ((col16 >> 2) & 1);
  const int soff = (quad ^ (col16 & 3)) << 3;

  int aoff[4], boff[4];
#pragma unroll
  for (int t = 0; t < 4; t++) {
    aoff[t] = (wm + t*16 + colp)*32 + soff;
    boff[t] = 4096 + (wn + t*16 + colp)*32 + soff;
  }
  floatx4 acc[4][4];
#pragma unroll
  for (int i = 0; i < 4; i++)
#pragma unroll
    for (int j = 0; j < 4; j++) acc[i][j] = (floatx4){0.f, 0.f, 0.f, 0.f};

  if (fid >= 276 && fid < 404) {
    // ---- gram ----
    const int g = xcd_chunk(fid - 276, 128);
    const int m0 = (g & 3) * 128, n0 = ((g >> 2) & 3) * 128;
    const long kz = (long)(g >> 4) * 576;
    long abase[2], bbase[2]; int ldso[2];
#pragma unroll
    for (int r = 0; r < 2; r++) {
      const int idx = r*256 + tid;
      const int rowp = idx >> 2;
      const int row = rowp ^ ((rowp >> 2) & 1);
      const int kc = (((idx & 3) ^ (row & 3)) << 3);
      abase[r] = (long)(m0 + row)*4608 + kz + kc;
      bbase[r] = (long)(n0 + row)*4608 + kz + kc;
      ldso[r] = idx << 3;
    }
#define STAGE_GRAM(s_) do { \
      const int kk_ = (s_) << 5; \
      const int lo_ = ((s_) % 3) * 8192; \
      gl_lds16(wb + (abase[0] + kk_), smem + lo_ + ldso[0]); \
      gl_lds16(wb + (abase[1] + kk_), smem + lo_ + ldso[1]); \
      gl_lds16(wb + (bbase[0] + kk_), smem + lo_ + 4096 + ldso[0]); \
      gl_lds16(wb + (bbase[1] + kk_), smem + lo_ + 4096 + ldso[1]); \
    } while (0)
    STAGE_GRAM(0);
    STAGE_GRAM(1);
    for (int s = 0; s < 18; ++s) {
      if (s + 1 < 18) asm volatile("s_waitcnt vmcnt(4)\n\ts_barrier" ::: "memory");
      else            asm volatile("s_waitcnt vmcnt(0)\n\ts_barrier" ::: "memory");
      if (s + 2 < 18) STAGE_GRAM(s + 2);
      const int lo = (s % 3) * 8192;
      short8 af[4], bfr[4];
#pragma unroll
      for (int t = 0; t < 4; t++) {
        af[t]  = *(const short8*)(smem + lo + aoff[t]);
        bfr[t] = *(const short8*)(smem + lo + boff[t]);
      }
#pragma unroll
      for (int i = 0; i < 4; i++)
#pragma unroll
        for (int j = 0; j < 4; j++)
          acc[i][j] = __builtin_amdgcn_mfma_f32_16x16x32_bf16(af[i], bfr[j], acc[i][j], 0, 0, 0);
    }
    float* pg = pgram + (size_t)(g >> 4) * 262144;
#pragma unroll
    for (int i = 0; i < 4; i++)
#pragma unroll
      for (int j = 0; j < 4; j++) {
        const int m = m0 + wm + i*16 + (quad << 2);
        const int n = n0 + wn + j*16 + col16;
#pragma unroll
        for (int r = 0; r < 4; r++) pg[(size_t)(m + r)*512 + n] = acc[i][j][r];
      }
    return;
  }

  // ---- conv ----
  int cls, lb;
  if (fid < 276)      { cls = 0; lb = fid; }
  else if (fid < 668) { cls = 1; lb = fid - 404; }
  else if (fid < 932) { cls = 2; lb = fid - 668; }
  else                { cls = 3; lb = fid - 932; }
  const int lg = xcd_chunk(lb, c_cnt[cls]);
  const int mb = lg >> 2, nb = lg & 3;
  const int xlim = c_xlim[cls];
  const int npix = c_ylim[cls] * xlim;
  const int M = NB * npix;
  const int m0 = mb * 128, n0 = nb * 128;
  const int t0 = c_tap0[cls];
  const int ntap = c_ntap[cls];

  long abase[2], bbase[2]; int ldso[2];
#pragma unroll
  for (int r = 0; r < 2; r++) {
    const int idx = r*256 + tid;
    const int rowp = idx >> 2;
    const int row = rowp ^ ((rowp >> 2) & 1);
    const int kc = (((idx & 3) ^ (row & 3)) << 3);
    int rm = m0 + row; if (rm >= M) rm = 0;
    const int b = rm / npix; const int rem = rm - b*npix;
    const int yy = rem / xlim; const int xx = rem - yy*xlim;
    abase[r] = ((long)(b*34 + yy + 1)*34 + (xx + 1))*512 + kc;
    bbase[r] = ((long)(t0*512 + n0 + row))*512 + kc;
    ldso[r] = idx << 3;
  }

  const int nst = ntap << 4;
#define STAGE_CONV(s_) do { \
    const int tap_ = t0 + ((s_) >> 4); \
    const long adel_ = (long)((c_dy[tap_]*34 + c_dx[tap_])*512); \
    const long bdel_ = (long)((s_) >> 4) << 18; \
    const int kk_ = ((s_) & 15) << 5; \
    const int lo_ = ((s_) % 3) * 8192; \
    gl_lds16(xs + (abase[0] + adel_ + kk_), smem + lo_ + ldso[0]); \
    gl_lds16(xs + (abase[1] + adel_ + kk_), smem + lo_ + ldso[1]); \
    gl_lds16(wrt + (bbase[0] + bdel_ + kk_), smem + lo_ + 4096 + ldso[0]); \
    gl_lds16(wrt + (bbase[1] + bdel_ + kk_), smem + lo_ + 4096 + ldso[1]); \
  } while (0)
  STAGE_CONV(0);
  STAGE_CONV(1);
  for (int s = 0; s < nst; ++s) {
    if (s + 1 < nst) asm volatile("s_waitcnt vmcnt(4)\n\ts_barrier" ::: "memory");
    else             asm volatile("s_waitcnt vmcnt(0)\n\ts_barrier" ::: "memory");
    if (s + 2 < nst) STAGE_CONV(s + 2);
    const int lo = (s % 3) * 8192;
    short8 af[4], bfr[4];
#pragma unroll
    for (int t = 0; t < 4; t++) {
      af[t]  = *(const short8*)(smem + lo + aoff[t]);
      bfr[t] = *(const short8*)(smem + lo + boff[t]);
    }
#pragma unroll
    for (int i = 0; i < 4; i++)
#pragma unroll
      for (int j = 0; j < 4; j++)
        acc[i][j] = __builtin_amdgcn_mfma_f32_16x16x32_bf16(af[i], bfr[j], acc[i][j], 0, 0, 0);
  }

  // epilogue: transpose 64 n-cols at a time through Ct[64][138] (stride 138 kills
  // the mod-4 bank alignment). Sync first: other waves may still be reading LDS.
  __syncthreads();
  __hip_bfloat16* plane = out1 + c_poff[cls];
#pragma unroll
  for (int h = 0; h < 2; h++) {
    if ((wv & 1) == h) {
#pragma unroll
      for (int i = 0; i < 4; i++) {
        const int mrow = wm + i*16 + (quad << 2);
#pragma unroll
        for (int j = 0; j < 4; j++) {
          const int ncl = j*16 + col16;
          ushort4 v;
          v.x = bf16b(acc[i][j][0]); v.y = bf16b(acc[i][j][1]);
          v.z = bf16b(acc[i][j][2]); v.w = bf16b(acc[i][j][3]);
          *(ushort4*)(smem + ncl*138 + mrow) = v;
        }
      }
    }
    __syncthreads();
#pragma unroll
    for (int it = 0; it < 4; it++) {
      const int c = it*256 + tid;
      const int ol = c >> 4, ml = (c & 15) << 3;
      const int mg = m0 + ml;
      if (mg < M) {
        const ushort4 v = *(const ushort4*)(smem + ol*138 + ml);
        *(ushort4*)(plane + (long)(n0 + h*64 + ol)*M + mg) = v;
      }
    }
    __syncthreads();
  }
}

// ---------------- K4: gram reduce+normalize (256) + blur+epilogue (4096) ----------------
__global__ __launch_bounds__(256) void k_blur(const __hip_bfloat16* __restrict__ out1,
    const float* __restrict__ dm, const float* __restrict__ noise,
    const float* __restrict__ nw, const float* __restrict__ fb, float* __restrict__ out,
    const float* __restrict__ pgram, const float* __restrict__ wni,
    float* __restrict__ co_out) {
  if (blockIdx.x < 256) {
    const int i4 = blockIdx.x*256 + threadIdx.x;
    float4 s = make_float4(0.f, 0.f, 0.f, 0.f);
#pragma unroll
    for (int z = 0; z < 8; z++) {
      const float4 v = ((const float4*)(pgram + (size_t)z*262144))[i4];
      s.x += v.x; s.y += v.y; s.z += v.z; s.w += v.w;
    }
    const float wm = wni[i4 >> 7];
    const float4 wn4 = ((const float4*)wni)[i4 & 127];
    float4 o;
    o.x = s.x*wm*wn4.x; o.y = s.y*wm*wn4.y; o.z = s.z*wm*wn4.z; o.w = s.w*wm*wn4.w;
    ((float4*)co_out)[i4] = o;
    return;
  }
  const int bo = blockIdx.x - 256;
  const int b = bo >> 9, o = bo & 511;
  __shared__ unsigned short L[65 * 68];
  const int tid = threadIdx.x;
  const unsigned short* p0 = (const unsigned short*)out1 + 0        + (long)o * 8712 + b * 1089;
  const unsigned short* p1 = (const unsigned short*)out1 + 4460544  + (long)o * 8448 + b * 1056;
  const unsigned short* p2 = (const unsigned short*)out1 + 8785920  + (long)o * 8448 + b * 1056;
  const unsigned short* p3 = (const unsigned short*)out1 + 13111296 + (long)o * 8192 + b * 1024;
  for (int m = tid; m < 65; m += 256) { L[m*68 + 0] = 0; L[m*68 + 66] = 0; }
  for (int e = tid; e < 1089; e += 256) { int y = e / 33, x = e - 33*y; L[(2*y)*68 + 2*x + 1] = p0[e]; }
  for (int e = tid; e < 1056; e += 256) { int y = e >> 5, x = e & 31;   L[(2*y)*68 + 2*x + 2] = p1[e]; }
  for (int e = tid; e < 1056; e += 256) { int y = e / 33, x = e - 33*y; L[(2*y+1)*68 + 2*x + 1] = p2[e]; }
  for (int e = tid; e < 1024; e += 256) { int y = e >> 5, x = e & 31;   L[(2*y+1)*68 + 2*x + 2] = p3[e]; }
  __syncthreads();
  const float dmv = dm[bo];
  const float nwv = nw[0];
  const float bv = fb[o];
  const int Q = tid & 63;
  const int qy = tid >> 6;
  const int mbase = 16 * qy - 1;
  float hs[18];
#pragma unroll
  for (int rm = 0; rm < 18; rm++) {
    const int m = mbase + rm;
    float s = 0.f;
    if (m >= 0 && m <= 64) {
      const unsigned short* row = L + m*68 + Q;
      s = 0.25f * (bfu(row[0]) + bfu(row[3])) + 0.75f * (bfu(row[1]) + bfu(row[2]));
    }
    hs[rm] = s;
  }
  float* op = out + ((size_t)bo << 12);
  const float* npl = noise + ((size_t)b << 12);
#pragma unroll
  for (int pp = 0; pp < 16; pp++) {
    const int P = 16 * qy + pp;
    float s = 0.25f * (hs[pp] + hs[pp + 3]) + 0.75f * (hs[pp + 1] + hs[pp + 2]);
    float v = fmaf(dmv, s, fmaf(nwv, npl[P * 64 + Q], bv));
    v = (v >= 0.f ? v : 0.2f * v) * 1.4142135623730951f;
    op[P * 64 + Q] = v;
  }
}

extern "C" void kernel_launch(void* const* d_in, const int* in_sizes, int n_in,
                              void* d_out, int out_size, void* d_ws, size_t ws_size,
                              hipStream_t stream) {
  const float* x       = (const float*)d_in[0];
  const float* co      = (const float*)d_in[1];
  const float* style   = (const float*)d_in[2];
  const float* noise   = (const float*)d_in[3];
  const float* W       = (const float*)d_in[4];
  const float* mb_w    = (const float*)d_in[5];
  const float* mb_b    = (const float*)d_in[6];
  const float* mod_w   = (const float*)d_in[7];
  const float* mod_b   = (const float*)d_in[8];
  const float* cluster = (const float*)d_in[9];
  const float* gate    = (const float*)d_in[10];
  const float* tmpr    = (const float*)d_in[11];
  const float* nw      = (const float*)d_in[12];
  const float* fb      = (const float*)d_in[13];
  float* out = (float*)d_out;
  char* ws = (char*)d_ws;

  __hip_bfloat16* xs   = (__hip_bfloat16*)(ws + O_XS);
  __hip_bfloat16* out1 = (__hip_bfloat16*)(ws + O_OUT1);
  __hip_bfloat16* wrt  = (__hip_bfloat16*)(ws + O_WRT);
  __hip_bfloat16* wb   = (__hip_bfloat16*)(ws + O_WB);
  float* pgram = (float*)(ws + O_PG);
  float* wsq = (float*)(ws + O_WSQ);
  float* gr  = (float*)(ws + O_GR);
  float* sb  = (float*)(ws + O_SB);
  float* st0 = (float*)(ws + O_ST0);
  float* wni = (float*)(ws + O_WNI);
  float* dm  = (float*)(ws + O_DM);
  float* pacc = (float*)(ws + O_STS);

  k_big1<<<1101, 256, 0, stream>>>(W, wsq, wni, wrt, (unsigned short*)wb,
                                   style, mod_w, mod_b, st0, co, gate,
                                   cluster, tmpr, mb_w, mb_b, gr, sb, pacc, xs);
  k_big2<<<1089, 256, 0, stream>>>(st0, gr, sb, wsq, dm, x, xs, pacc, out + OUT_L);
  k_mfma<<<1188, 256, 0, stream>>>(xs, wrt, out1, wb, pgram);
  k_blur<<<4352, 256, 0, stream>>>(out1, dm, noise, nw, fb, out, pgram, wni, out + OUT_CO);
}

// Round 5
// 239.460 us; speedup vs baseline: 1.3563x; 1.0039x over previous
//
#include <hip/hip_runtime.h>
#include <hip/hip_bf16.h>

#define NB 8
#define LIN_SCALE 0.044194173824159216f
#define SCALE 0.014731391274719736f

typedef __attribute__((ext_vector_type(8))) short short8;
typedef __attribute__((ext_vector_type(4))) float floatx4;

// ---------------- workspace layout (bytes) ----------------
static constexpr size_t O_XS   = 0;                   // 8*34*34*512 bf16 (zero-padded NHWC modulated x)
static constexpr size_t O_OUT1 = 9469952;             // parity planes bf16: 34,611,200
static constexpr size_t O_WRT  = 44081152;            // 9*512*512 bf16 wrt[tap][o][i]
static constexpr size_t O_WB   = 48799744;            // 512*4608 bf16 wb[o][k]
static constexpr size_t O_PG   = 53518336;            // 8*512*512 f32 gram partials
static constexpr size_t O_WSQ  = 61906944;            // 512*512 f32
static constexpr size_t O_CL   = 62955520;            // (unused; layout stability)
static constexpr size_t O_GR   = O_CL + 32768;
static constexpr size_t O_SB   = O_GR + 32768;
static constexpr size_t O_ST0  = O_SB + 1024;
static constexpr size_t O_STS  = O_ST0 + 16384;       // pacc (loss partials, 4 KB)
static constexpr size_t O_ST2  = O_STS + 16384;       // unused
static constexpr size_t O_WNI  = O_ST2 + 16384;
static constexpr size_t O_DM   = O_WNI + 2048;
static constexpr size_t O_ACC  = O_DM + 16384;

static constexpr size_t OUT_CO = 16777216;            // d_out offset of co_out (floats)
static constexpr size_t OUT_L  = 17039360;            // d_out offset of losses (floats)

// parity-class tables for the transposed conv (gather form, wf[k]=W[2-k] folded)
__device__ const int c_ylim[4] = {33,33,32,32};
__device__ const int c_xlim[4] = {33,32,33,32};
__device__ const int c_ntap[4] = {4,2,2,1};
__device__ const int c_tap0[4] = {0,4,6,8};
__device__ const int c_nmb[4]  = {69,66,66,64};       // ceil(M/128)
__device__ const int c_cnt[4]  = {276,264,264,256};   // nmb*4
__device__ const int c_dy[9] = {-1,-1,0,0, -1,0, 0,0, 0};
__device__ const int c_dx[9] = {-1,0,-1,0, 0,0, -1,0, 0};
__device__ const int c_ky[9] = {2,2,0,0, 2,0, 1,1, 1};
__device__ const int c_kx[9] = {2,0,2,0, 1,1, 2,0, 1};
__device__ const long c_poff[4] = {0, 4460544, 8785920, 13111296};

__device__ __forceinline__ float wave_red(float v) {
#pragma unroll
  for (int s = 32; s > 0; s >>= 1) v += __shfl_down(v, s);
  return v;
}

__device__ __forceinline__ void gl_lds16(const void* g, void* l) {
  __builtin_amdgcn_global_load_lds((const __attribute__((address_space(1))) void*)g,
                                   (__attribute__((address_space(3))) void*)l, 16, 0, 0);
}

__device__ __forceinline__ unsigned short bf16b(float f) {
  union { __hip_bfloat16 h; unsigned short u; } cv;
  cv.h = __float2bfloat16(f);
  return cv.u;
}

__device__ __forceinline__ float bfu(unsigned short u) {
  union { float f; unsigned u32; } c; c.u32 = ((unsigned)u) << 16; return c.f;
}

// bijective chunked XCD swizzle (m204)
__device__ __forceinline__ int xcd_chunk(int lb, int cnt) {
  const int q = cnt >> 3, r = cnt & 7;
  const int c = lb & 7, i = lb >> 3;
  return (c < r) ? c*(q+1) + i : r*(q+1) + (c - r)*q + i;
}

// ---------------- K1: wproc(512) + st0(64) + losses(512) + prep(1) + xs-border-zero(12) ----------------
__global__ __launch_bounds__(256) void k_big1(const float* __restrict__ W,
    float* __restrict__ wsq, float* __restrict__ wni,
    __hip_bfloat16* __restrict__ wrt, unsigned short* __restrict__ wb,
    const float* __restrict__ style, const float* __restrict__ mod_w,
    const float* __restrict__ mod_b, float* __restrict__ st0,
    const float* __restrict__ co, const float* __restrict__ gate,
    const float* __restrict__ cluster, const float* __restrict__ tmpr,
    const float* __restrict__ mb_w, const float* __restrict__ mb_b,
    float* __restrict__ gr, float* __restrict__ sb,
    float* __restrict__ pacc, __hip_bfloat16* __restrict__ xs) {
  __shared__ float sh[8192];
  __shared__ float extra[8];
  const int bid = blockIdx.x, tid = threadIdx.x;
  const int lane = tid & 63, wv = tid >> 6;
  if (bid < 512) {
    const int o = bid;
    for (int j = tid; j < 4608; j += 256) sh[j] = W[(size_t)o*4608 + j];
    __syncthreads();
    float tot = 0.f;
#pragma unroll
    for (int half = 0; half < 2; half++) {
      const int i = tid + half*256;
      float s = 0.f;
#pragma unroll
      for (int k = 0; k < 9; k++) { float w = sh[i*9 + k]; s = fmaf(w, w, s); }
      wsq[o*512 + i] = s; tot += s;
#pragma unroll
      for (int tp = 0; tp < 9; tp++)
        wrt[((size_t)tp*512 + o)*512 + i] = __float2bfloat16(sh[i*9 + c_ky[tp]*3 + c_kx[tp]]);
    }
    for (int j = tid; j < 4608; j += 256) wb[(size_t)o*4608 + j] = bf16b(sh[j]);
    tot = wave_red(tot);
    if (lane == 0) extra[wv] = tot;
    __syncthreads();
    if (tid == 0) wni[o] = 1.f / fmaxf(sqrtf(extra[0]+extra[1]+extra[2]+extra[3]), 1e-12f);
  } else if (bid < 576) {
    const int b = (bid - 512) >> 3, oc = (bid - 512) & 7;
    sh[tid] = style[b*1024 + 512 + tid];
    sh[tid + 256] = style[b*1024 + 768 + tid];
    __syncthreads();
#pragma unroll
    for (int rr = 0; rr < 16; rr++) {
      const int c = oc*64 + wv*16 + rr;
      const float* mw = mod_w + (size_t)c*512;
      float acc = 0.f;
#pragma unroll
      for (int it = 0; it < 8; it++) acc = fmaf(mw[lane + 64*it], sh[lane + 64*it], acc);
      acc = wave_red(acc);
      if (lane == 0) st0[b*512 + c] = acc*LIN_SCALE + mod_b[c];
    }
  } else if (bid < 1088) {
    // losses: recompute cl locally
    const int i = bid - 576;
    const float tt = 5.f / (1.f + expf(-tmpr[0]));
    const float gg = 1.f / (1.f + expf(-gate[0]));
    for (int j = tid; j < 512; j += 256) {
      float v[16]; float m = -1e30f;
#pragma unroll
      for (int g = 0; g < 16; g++) { v[g] = tt * cluster[g*512 + j]; m = fmaxf(m, v[g]); }
      float s = 0.f;
#pragma unroll
      for (int g = 0; g < 16; g++) { v[g] = expf(v[g] - m); s += v[g]; }
      float inv = 1.f / s;
#pragma unroll
      for (int g = 0; g < 16; g++) sh[g*512 + j] = v[g] * inv;
    }
    __syncthreads();
    float cli[16];
#pragma unroll
    for (int k = 0; k < 16; k++) cli[k] = sh[k*512 + i];
    float p1 = 0.f, p2 = 0.f;
    for (int j = tid; j < 512; j += 256) {
      float d = 0.f;
#pragma unroll
      for (int k = 0; k < 16; k++) d = fmaf(cli[k], sh[k*512 + j], d);
      float S = 1.f / (1.f + expf(-50.f*(co[i*512 + j] - gg)));
      float e = d - S;
      p1 = fmaf(e, e, p1); p2 += S;
    }
    p1 = wave_red(p1); p2 = wave_red(p2);
    if (lane == 0) { extra[wv] = p1; extra[4 + wv] = p2; }
    __syncthreads();
    if (tid == 0)  pacc[i]       = extra[0]+extra[1]+extra[2]+extra[3];
    if (tid == 64) pacc[512 + i] = extra[4]+extra[5]+extra[6]+extra[7];
  } else if (bid == 1088) {
    // prep: gr + sb
    const float tt = 5.f / (1.f + expf(-tmpr[0]));
#pragma unroll
    for (int h = 0; h < 2; h++) {
      const int c = tid + h*256;
      float v[16]; float m = -1e30f;
#pragma unroll
      for (int g = 0; g < 16; g++) { v[g] = tt * cluster[g*512 + c]; m = fmaxf(m, v[g]); }
      float s = 0.f;
#pragma unroll
      for (int g = 0; g < 16; g++) { v[g] = expf(v[g] - m); s += v[g]; }
      float inv = 1.f / s;
      float clv[16]; float m2 = -1e30f;
#pragma unroll
      for (int g = 0; g < 16; g++) { clv[g] = v[g]*inv; m2 = fmaxf(m2, 500.f*clv[g]); }
      float s2 = 0.f; float e2[16];
#pragma unroll
      for (int g = 0; g < 16; g++) { e2[g] = expf(500.f*clv[g] - m2); s2 += e2[g]; }
      float i2 = 1.f / s2;
#pragma unroll
      for (int g = 0; g < 16; g++) gr[g*512 + c] = rintf(e2[g]*i2) + 1e-6f;
    }
    for (int task = wv; task < 128; task += 4) {
      int b = task >> 4, g = task & 15;
      const float* s1 = style + b*1024;
      const float* mw = mb_w + g*512;
      float acc = 0.f;
#pragma unroll
      for (int it = 0; it < 8; it++) acc = fmaf(s1[lane + 64*it], mw[lane + 64*it], acc);
      acc = wave_red(acc);
      if (lane == 0) sb[b*16 + g] = acc*LIN_SCALE + mb_b[g];
    }
  } else {
    // zero the xs border ring (1.08 MB)
    const int id0 = (bid - 1089)*256 + tid;
    const float4 z = make_float4(0.f, 0.f, 0.f, 0.f);
    float4* xq = (float4*)xs;
#pragma unroll
    for (int it = 0; it < 22; ++it) {
      const int id = id0 + it*3072;
      const int c = id & 63;
      const int pb = id >> 6;
      const int b = pb / 132;
      const int pix = pb - b*132;
      int y, xx;
      if (pix < 34)       { y = 0;        xx = pix; }
      else if (pix < 68)  { y = 33;       xx = pix - 34; }
      else if (pix < 100) { y = pix - 67; xx = 0; }
      else                { y = pix - 99; xx = 33; }
      xq[((size_t)(b*34 + y)*34 + xx)*64 + c] = z;
    }
  }
}

// ---------------- K2: demod(64) + xsprep(1024) + loss-reduce(1); style-mix inline ----------------
__global__ __launch_bounds__(256) void k_big2(const float* __restrict__ st0,
    const float* __restrict__ gr, const float* __restrict__ sb,
    const float* __restrict__ wsq, float* __restrict__ dm,
    const float* __restrict__ x, __hip_bfloat16* __restrict__ xs,
    const float* __restrict__ pacc, float* __restrict__ out_tail) {
  __shared__ float L[64*65];
  __shared__ float red[16][4];
  __shared__ float inv[16];
  __shared__ float sbb[16];
  const int tid = threadIdx.x;
  const int lane = tid & 63, wv = tid >> 6;

  if (blockIdx.x == 1088) {
    float a = pacc[tid] + pacc[tid + 256];
    float b2 = pacc[512 + tid] + pacc[768 + tid];
    a = wave_red(a); b2 = wave_red(b2);
    if (lane == 0) { red[0][wv] = a; red[1][wv] = b2; }
    __syncthreads();
    if (tid == 0) {
      float p1 = red[0][0]+red[0][1]+red[0][2]+red[0][3];
      float p2 = red[1][0]+red[1][1]+red[1][2]+red[1][3];
      out_tail[0] = p1;
      float d = 16384.f - p2;
      out_tail[1] = d*d;
    }
    return;
  }

  const int b = (blockIdx.x < 64) ? (blockIdx.x >> 3) : ((blockIdx.x - 64) >> 7);
  float s0 = st0[b*512 + tid], s1 = st0[b*512 + 256 + tid];
  float g0[16], g1[16];
#pragma unroll
  for (int g = 0; g < 16; g++) { g0[g] = gr[g*512 + tid]; g1[g] = gr[g*512 + 256 + tid]; }
#pragma unroll
  for (int g = 0; g < 16; g++) {
    float a = g0[g]*s0, c = g1[g]*s1;
    float p = wave_red(a*a + c*c);
    if (lane == 0) red[g][wv] = p;
  }
  if (tid < 16) sbb[tid] = sb[b*16 + tid];
  __syncthreads();
  if (tid < 16) {
    float ttn = red[tid][0] + red[tid][1] + red[tid][2] + red[tid][3];
    inv[tid] = 1.f / fmaxf(sqrtf(ttn), 1e-12f);
  }
  __syncthreads();
  float f0 = 0.f, f1 = 0.f;
#pragma unroll
  for (int g = 0; g < 16; g++) {
    float w = inv[g]*sbb[g];
    f0 = fmaf(g0[g], w, f0); f1 = fmaf(g1[g], w, f1);
  }
  const float sn0 = s0*f0, sn1 = s1*f1;

  if (blockIdx.x < 64) {
    const int oc = blockIdx.x & 7;
    L[tid] = sn0*sn0;
    L[tid + 256] = sn1*sn1;
    __syncthreads();
#pragma unroll
    for (int rr = 0; rr < 16; rr++) {
      const int o = oc*64 + wv*16 + rr;
      const float* wp = wsq + (size_t)o*512;
      float acc = 0.f;
#pragma unroll
      for (int it = 0; it < 8; it++) acc = fmaf(wp[lane + 64*it], L[lane + 64*it], acc);
      acc = wave_red(acc);
      if (lane == 0) dm[b*512 + o] = rsqrtf((1.0f/4608.0f)*acc + 1e-8f);
    }
    return;
  }

  // xsprep: sts broadcast via L, save this thread's 2 scales, then tile x via float4
  L[tid] = sn0*SCALE;
  L[tid + 256] = sn1*SCALE;
  __syncthreads();
  const int id = blockIdx.x - 64;
  const int p0 = ((id >> 3) & 15) * 64;
  const int i0 = (id & 7) * 64;
  const int iw2 = (tid & 31) * 2, pw = tid >> 5;
  const float sv0 = L[i0 + iw2];
  const float sv1 = L[i0 + iw2 + 1];
  __syncthreads();
  const int cg = (tid & 15) * 4, ir = tid >> 4;
  const float* xp = x + ((size_t)b*512 + i0)*1024 + p0;
  float4 xv[4];
#pragma unroll
  for (int ii = 0; ii < 4; ii++) {
    const int i = ir + 16*ii;
    xv[ii] = *(const float4*)(xp + (size_t)i*1024 + cg);
  }
#pragma unroll
  for (int ii = 0; ii < 4; ii++) {
    const int i = ir + 16*ii;
    L[i*65 + cg + 0] = xv[ii].x;
    L[i*65 + cg + 1] = xv[ii].y;
    L[i*65 + cg + 2] = xv[ii].z;
    L[i*65 + cg + 3] = xv[ii].w;
  }
  __syncthreads();
#pragma unroll
  for (int pp = 0; pp < 8; pp++) {
    const int po = pw + 8*pp;
    const int pix = p0 + po;
    const int y = pix >> 5, xq = pix & 31;
    ushort2 w;
    w.x = bf16b(L[iw2*65 + po] * sv0);
    w.y = bf16b(L[(iw2+1)*65 + po] * sv1);
    *(ushort2*)((unsigned short*)xs + (((size_t)b*34 + (y+1))*34 + (xq+1))*512 + i0 + iw2) = w;
  }
}

// ---------------- K3: conv MFMA (1060) + gram MFMA (128), 1188 blocks ----------------
// Triple-buffered LDS, single barrier/step, counted vmcnt(4) (T3/T4). Buffer offsets
// via SALU rotate (no %3). T5 setprio(1) around the MFMA cluster: 3 independent
// blocks/CU at different pipeline phases = wave role diversity (m218b prerequisite).
__global__ __launch_bounds__(256, 3) void k_mfma(
    const __hip_bfloat16* __restrict__ xs, const __hip_bfloat16* __restrict__ wrt,
    __hip_bfloat16* __restrict__ out1, const __hip_bfloat16* __restrict__ wb,
    float* __restrict__ pgram) {
  __shared__ __hip_bfloat16 smem[24576];
  const int fid = blockIdx.x;
  const int tid = threadIdx.x;
  const int lane = tid & 63, wv = tid >> 6;
  const int wm = (wv >> 1) << 6, wn = (wv & 1) << 6;
  const int col16 = lane & 15, quad = lane >> 4;
  const int colp = col16 ^ ((col16 >> 2) & 1);
  const int soff = (quad ^ (col16 & 3)) << 3;

  int aoff[4], boff[4];
#pragma unroll
  for (int t = 0; t < 4; t++) {
    aoff[t] = (wm + t*16 + colp)*32 + soff;
    boff[t] = 4096 + (wn + t*16 + colp)*32 + soff;
  }
  floatx4 acc[4][4];
#pragma unroll
  for (int i = 0; i < 4; i++)
#pragma unroll
    for (int j = 0; j < 4; j++) acc[i][j] = (floatx4){0.f, 0.f, 0.f, 0.f};

  if (fid >= 276 && fid < 404) {
    // ---- gram ----
    const int g = xcd_chunk(fid - 276, 128);
    const int m0 = (g & 3) * 128, n0 = ((g >> 2) & 3) * 128;
    const long kz = (long)(g >> 4) * 576;
    long abase[2], bbase[2]; int ldso[2];
#pragma unroll
    for (int r = 0; r < 2; r++) {
      const int idx = r*256 + tid;
      const int rowp = idx >> 2;
      const int row = rowp ^ ((rowp >> 2) & 1);
      const int kc = (((idx & 3) ^ (row & 3)) << 3);
      abase[r] = (long)(m0 + row)*4608 + kz + kc;
      bbase[r] = (long)(n0 + row)*4608 + kz + kc;
      ldso[r] = idx << 3;
    }
#define STAGE_GRAM(s_, lo_) do { \
      const int kk_ = (s_) << 5; \
      gl_lds16(wb + (abase[0] + kk_), smem + (lo_) + ldso[0]); \
      gl_lds16(wb + (abase[1] + kk_), smem + (lo_) + ldso[1]); \
      gl_lds16(wb + (bbase[0] + kk_), smem + (lo_) + 4096 + ldso[0]); \
      gl_lds16(wb + (bbase[1] + kk_), smem + (lo_) + 4096 + ldso[1]); \
    } while (0)
    STAGE_GRAM(0, 0);
    STAGE_GRAM(1, 8192);
    int loC = 0, loS = 16384;
    for (int s = 0; s < 18; ++s) {
      if (s + 1 < 18) asm volatile("s_waitcnt vmcnt(4)\n\ts_barrier" ::: "memory");
      else            asm volatile("s_waitcnt vmcnt(0)\n\ts_barrier" ::: "memory");
      if (s + 2 < 18) STAGE_GRAM(s + 2, loS);
      short8 af[4], bfr[4];
#pragma unroll
      for (int t = 0; t < 4; t++) {
        af[t]  = *(const short8*)(smem + loC + aoff[t]);
        bfr[t] = *(const short8*)(smem + loC + boff[t]);
      }
      __builtin_amdgcn_s_setprio(1);
#pragma unroll
      for (int i = 0; i < 4; i++)
#pragma unroll
        for (int j = 0; j < 4; j++)
          acc[i][j] = __builtin_amdgcn_mfma_f32_16x16x32_bf16(af[i], bfr[j], acc[i][j], 0, 0, 0);
      __builtin_amdgcn_s_setprio(0);
      loC = (loC == 16384) ? 0 : loC + 8192;
      loS = (loS == 16384) ? 0 : loS + 8192;
    }
    float* pg = pgram + (size_t)(g >> 4) * 262144;
#pragma unroll
    for (int i = 0; i < 4; i++)
#pragma unroll
      for (int j = 0; j < 4; j++) {
        const int m = m0 + wm + i*16 + (quad << 2);
        const int n = n0 + wn + j*16 + col16;
#pragma unroll
        for (int r = 0; r < 4; r++) pg[(size_t)(m + r)*512 + n] = acc[i][j][r];
      }
    return;
  }

  // ---- conv ----
  int cls, lb;
  if (fid < 276)      { cls = 0; lb = fid; }
  else if (fid < 668) { cls = 1; lb = fid - 404; }
  else if (fid < 932) { cls = 2; lb = fid - 668; }
  else                { cls = 3; lb = fid - 932; }
  const int lg = xcd_chunk(lb, c_cnt[cls]);
  const int mb = lg >> 2, nb = lg & 3;
  const int xlim = c_xlim[cls];
  const int npix = c_ylim[cls] * xlim;
  const int M = NB * npix;
  const int m0 = mb * 128, n0 = nb * 128;
  const int t0 = c_tap0[cls];
  const int ntap = c_ntap[cls];

  long abase[2], bbase[2]; int ldso[2];
#pragma unroll
  for (int r = 0; r < 2; r++) {
    const int idx = r*256 + tid;
    const int rowp = idx >> 2;
    const int row = rowp ^ ((rowp >> 2) & 1);
    const int kc = (((idx & 3) ^ (row & 3)) << 3);
    int rm = m0 + row; if (rm >= M) rm = 0;
    const int b = rm / npix; const int rem = rm - b*npix;
    const int yy = rem / xlim; const int xx = rem - yy*xlim;
    abase[r] = ((long)(b*34 + yy + 1)*34 + (xx + 1))*512 + kc;
    bbase[r] = ((long)(t0*512 + n0 + row))*512 + kc;
    ldso[r] = idx << 3;
  }

  const int nst = ntap << 4;
#define STAGE_CONV(s_, lo_) do { \
    const int tap_ = t0 + ((s_) >> 4); \
    const long adel_ = (long)((c_dy[tap_]*34 + c_dx[tap_])*512); \
    const long bdel_ = (long)((s_) >> 4) << 18; \
    const int kk_ = ((s_) & 15) << 5; \
    gl_lds16(xs + (abase[0] + adel_ + kk_), smem + (lo_) + ldso[0]); \
    gl_lds16(xs + (abase[1] + adel_ + kk_), smem + (lo_) + ldso[1]); \
    gl_lds16(wrt + (bbase[0] + bdel_ + kk_), smem + (lo_) + 4096 + ldso[0]); \
    gl_lds16(wrt + (bbase[1] + bdel_ + kk_), smem + (lo_) + 4096 + ldso[1]); \
  } while (0)
  STAGE_CONV(0, 0);
  STAGE_CONV(1, 8192);
  int loC = 0, loS = 16384;
  for (int s = 0; s < nst; ++s) {
    if (s + 1 < nst) asm volatile("s_waitcnt vmcnt(4)\n\ts_barrier" ::: "memory");
    else             asm volatile("s_waitcnt vmcnt(0)\n\ts_barrier" ::: "memory");
    if (s + 2 < nst) STAGE_CONV(s + 2, loS);
    short8 af[4], bfr[4];
#pragma unroll
    for (int t = 0; t < 4; t++) {
      af[t]  = *(const short8*)(smem + loC + aoff[t]);
      bfr[t] = *(const short8*)(smem + loC + boff[t]);
    }
    __builtin_amdgcn_s_setprio(1);
#pragma unroll
    for (int i = 0; i < 4; i++)
#pragma unroll
      for (int j = 0; j < 4; j++)
        acc[i][j] = __builtin_amdgcn_mfma_f32_16x16x32_bf16(af[i], bfr[j], acc[i][j], 0, 0, 0);
    __builtin_amdgcn_s_setprio(0);
    loC = (loC == 16384) ? 0 : loC + 8192;
    loS = (loS == 16384) ? 0 : loS + 8192;
  }

  // epilogue: transpose 64 n-cols at a time through Ct[64][138]
  __syncthreads();
  __hip_bfloat16* plane = out1 + c_poff[cls];
#pragma unroll
  for (int h = 0; h < 2; h++) {
    if ((wv & 1) == h) {
#pragma unroll
      for (int i = 0; i < 4; i++) {
        const int mrow = wm + i*16 + (quad << 2);
#pragma unroll
        for (int j = 0; j < 4; j++) {
          const int ncl = j*16 + col16;
          ushort4 v;
          v.x = bf16b(acc[i][j][0]); v.y = bf16b(acc[i][j][1]);
          v.z = bf16b(acc[i][j][2]); v.w = bf16b(acc[i][j][3]);
          *(ushort4*)(smem + ncl*138 + mrow) = v;
        }
      }
    }
    __syncthreads();
#pragma unroll
    for (int it = 0; it < 4; it++) {
      const int c = it*256 + tid;
      const int ol = c >> 4, ml = (c & 15) << 3;
      const int mg = m0 + ml;
      if (mg < M) {
        const ushort4 v = *(const ushort4*)(smem + ol*138 + ml);
        *(ushort4*)(plane + (long)(n0 + h*64 + ol)*M + mg) = v;
      }
    }
    __syncthreads();
  }
}

// ---------------- K4: gram reduce+normalize (256) + blur+epilogue (4096) ----------------
// Blur restructured: horizontal pass -> f32 H-plane in LDS; vertical pass + noise +
// store all float4 (stores were scalar dword). Same fp ops/order => bit-identical.
__global__ __launch_bounds__(256) void k_blur(const __hip_bfloat16* __restrict__ out1,
    const float* __restrict__ dm, const float* __restrict__ noise,
    const float* __restrict__ nw, const float* __restrict__ fb, float* __restrict__ out,
    const float* __restrict__ pgram, const float* __restrict__ wni,
    float* __restrict__ co_out) {
  if (blockIdx.x < 256) {
    const int i4 = blockIdx.x*256 + threadIdx.x;
    float4 s = make_float4(0.f, 0.f, 0.f, 0.f);
#pragma unroll
    for (int z = 0; z < 8; z++) {
      const float4 v = ((const float4*)(pgram + (size_t)z*262144))[i4];
      s.x += v.x; s.y += v.y; s.z += v.z; s.w += v.w;
    }
    const float wm = wni[i4 >> 7];
    const float4 wn4 = ((const float4*)wni)[i4 & 127];
    float4 o;
    o.x = s.x*wm*wn4.x; o.y = s.y*wm*wn4.y; o.z = s.z*wm*wn4.z; o.w = s.w*wm*wn4.w;
    ((float4*)co_out)[i4] = o;
    return;
  }
  const int bo = blockIdx.x - 256;
  const int b = bo >> 9, o = bo & 511;
  __shared__ unsigned short L[65 * 68];   // [m][q+1], cols 0 and 66 zero guards
  __shared__ float Hs[67 * 64];           // horizontal pass, rows 0..66 = m -1..65
  const int tid = threadIdx.x;
  const unsigned short* p0 = (const unsigned short*)out1 + 0        + (long)o * 8712 + b * 1089;
  const unsigned short* p1 = (const unsigned short*)out1 + 4460544  + (long)o * 8448 + b * 1056;
  const unsigned short* p2 = (const unsigned short*)out1 + 8785920  + (long)o * 8448 + b * 1056;
  const unsigned short* p3 = (const unsigned short*)out1 + 13111296 + (long)o * 8192 + b * 1024;
  for (int m = tid; m < 65; m += 256) { L[m*68 + 0] = 0; L[m*68 + 66] = 0; }
  if (tid < 64) { Hs[tid] = 0.f; Hs[66*64 + tid] = 0.f; }
  for (int e = tid; e < 1089; e += 256) { int y = e / 33, x = e - 33*y; L[(2*y)*68 + 2*x + 1] = p0[e]; }
  for (int e2 = tid; e2 < 528; e2 += 256) {      // p1: width 32, 4B-aligned pairs
    const int e = e2*2; const int y = e >> 5, x = e & 31;
    const ushort2 u = *(const ushort2*)(p1 + e);
    L[(2*y)*68 + 2*x + 2] = u.x; L[(2*y)*68 + 2*x + 4] = u.y;
  }
  for (int e = tid; e < 1056; e += 256) { int y = e / 33, x = e - 33*y; L[(2*y+1)*68 + 2*x + 1] = p2[e]; }
  for (int e2 = tid; e2 < 512; e2 += 256) {      // p3: width 32, 4B-aligned pairs
    const int e = e2*2; const int y = e >> 5, x = e & 31;
    const ushort2 u = *(const ushort2*)(p3 + e);
    L[(2*y+1)*68 + 2*x + 2] = u.x; L[(2*y+1)*68 + 2*x + 4] = u.y;
  }
  __syncthreads();
  // horizontal pass: Hs[m+1][q], m=0..64, q=0..63
  for (int e = tid; e < 4160; e += 256) {
    const int m = e >> 6, q = e & 63;
    const unsigned short* row = L + m*68 + q;
    Hs[(m+1)*64 + q] = 0.25f * (bfu(row[0]) + bfu(row[3])) + 0.75f * (bfu(row[1]) + bfu(row[2]));
  }
  __syncthreads();
  const float dmv = dm[bo];
  const float nwv = nw[0];
  const float bv = fb[o];
  const int qx = (tid & 15) << 2;
  const int py = tid >> 4;
  float* op = out + ((size_t)bo << 12);
  const float* npl = noise + ((size_t)b << 12);
#pragma unroll
  for (int pp = 0; pp < 4; pp++) {
    const int P = py + (pp << 4);
    const float4 h0 = *(const float4*)(Hs + (P    )*64 + qx);   // m = P-1
    const float4 h1 = *(const float4*)(Hs + (P + 1)*64 + qx);
    const float4 h2 = *(const float4*)(Hs + (P + 2)*64 + qx);
    const float4 h3 = *(const float4*)(Hs + (P + 3)*64 + qx);
    const float4 n4 = *(const float4*)(npl + P*64 + qx);
    float4 ov;
    float s;
    s = 0.25f*(h0.x + h3.x) + 0.75f*(h1.x + h2.x);
    ov.x = fmaf(dmv, s, fmaf(nwv, n4.x, bv)); ov.x = (ov.x >= 0.f ? ov.x : 0.2f*ov.x) * 1.4142135623730951f;
    s = 0.25f*(h0.y + h3.y) + 0.75f*(h1.y + h2.y);
    ov.y = fmaf(dmv, s, fmaf(nwv, n4.y, bv)); ov.y = (ov.y >= 0.f ? ov.y : 0.2f*ov.y) * 1.4142135623730951f;
    s = 0.25f*(h0.z + h3.z) + 0.75f*(h1.z + h2.z);
    ov.z = fmaf(dmv, s, fmaf(nwv, n4.z, bv)); ov.z = (ov.z >= 0.f ? ov.z : 0.2f*ov.z) * 1.4142135623730951f;
    s = 0.25f*(h0.w + h3.w) + 0.75f*(h1.w + h2.w);
    ov.w = fmaf(dmv, s, fmaf(nwv, n4.w, bv)); ov.w = (ov.w >= 0.f ? ov.w : 0.2f*ov.w) * 1.4142135623730951f;
    *(float4*)(op + P*64 + qx) = ov;
  }
}

extern "C" void kernel_launch(void* const* d_in, const int* in_sizes, int n_in,
                              void* d_out, int out_size, void* d_ws, size_t ws_size,
                              hipStream_t stream) {
  const float* x       = (const float*)d_in[0];
  const float* co      = (const float*)d_in[1];
  const float* style   = (const float*)d_in[2];
  const float* noise   = (const float*)d_in[3];
  const float* W       = (const float*)d_in[4];
  const float* mb_w    = (const float*)d_in[5];
  const float* mb_b    = (const float*)d_in[6];
  const float* mod_w   = (const float*)d_in[7];
  const float* mod_b   = (const float*)d_in[8];
  const float* cluster = (const float*)d_in[9];
  const float* gate    = (const float*)d_in[10];
  const float* tmpr    = (const float*)d_in[11];
  const float* nw      = (const float*)d_in[12];
  const float* fb      = (const float*)d_in[13];
  float* out = (float*)d_out;
  char* ws = (char*)d_ws;

  __hip_bfloat16* xs   = (__hip_bfloat16*)(ws + O_XS);
  __hip_bfloat16* out1 = (__hip_bfloat16*)(ws + O_OUT1);
  __hip_bfloat16* wrt  = (__hip_bfloat16*)(ws + O_WRT);
  __hip_bfloat16* wb   = (__hip_bfloat16*)(ws + O_WB);
  float* pgram = (float*)(ws + O_PG);
  float* wsq = (float*)(ws + O_WSQ);
  float* gr  = (float*)(ws + O_GR);
  float* sb  = (float*)(ws + O_SB);
  float* st0 = (float*)(ws + O_ST0);
  float* wni = (float*)(ws + O_WNI);
  float* dm  = (float*)(ws + O_DM);
  float* pacc = (float*)(ws + O_STS);

  k_big1<<<1101, 256, 0, stream>>>(W, wsq, wni, wrt, (unsigned short*)wb,
                                   style, mod_w, mod_b, st0, co, gate,
                                   cluster, tmpr, mb_w, mb_b, gr, sb, pacc, xs);
  k_big2<<<1089, 256, 0, stream>>>(st0, gr, sb, wsq, dm, x, xs, pacc, out + OUT_L);
  k_mfma<<<1188, 256, 0, stream>>>(xs, wrt, out1, wb, pgram);
  k_blur<<<4352, 256, 0, stream>>>(out1, dm, noise, nw, fb, out, pgram, wni, out + OUT_CO);
}

// Round 6
// 237.464 us; speedup vs baseline: 1.3677x; 1.0084x over previous
//
#include <hip/hip_runtime.h>
#include <hip/hip_bf16.h>

#define NB 8
#define LIN_SCALE 0.044194173824159216f
#define SCALE 0.014731391274719736f

typedef __attribute__((ext_vector_type(8))) short short8;
typedef __attribute__((ext_vector_type(4))) float floatx4;

// ---------------- workspace layout (bytes) ----------------
static constexpr size_t O_XS   = 0;                   // 8*34*34*512 bf16 (zero-padded NHWC modulated x)
static constexpr size_t O_OUT1 = 9469952;             // parity planes bf16: 34,611,200
static constexpr size_t O_WRT  = 44081152;            // 9*512*512 bf16 wrt[tap][o][i]
static constexpr size_t O_WB   = 48799744;            // (unused since r6 — gram reads wrt)
static constexpr size_t O_PG   = 53518336;            // 3*512*512 f32 gram partials (tap-slices)
static constexpr size_t O_WSQ  = 61906944;            // 512*512 f32
static constexpr size_t O_CL   = 62955520;            // (unused; layout stability)
static constexpr size_t O_GR   = O_CL + 32768;
static constexpr size_t O_SB   = O_GR + 32768;
static constexpr size_t O_ST0  = O_SB + 1024;
static constexpr size_t O_STS  = O_ST0 + 16384;       // pacc (loss partials, 4 KB)
static constexpr size_t O_ST2  = O_STS + 16384;       // unused
static constexpr size_t O_WNI  = O_ST2 + 16384;
static constexpr size_t O_DM   = O_WNI + 2048;
static constexpr size_t O_ACC  = O_DM + 16384;

static constexpr size_t OUT_CO = 16777216;            // d_out offset of co_out (floats)
static constexpr size_t OUT_L  = 17039360;            // d_out offset of losses (floats)

// parity-class tables for the transposed conv (gather form, wf[k]=W[2-k] folded)
__device__ const int c_ylim[4] = {33,33,32,32};
__device__ const int c_xlim[4] = {33,32,33,32};
__device__ const int c_ntap[4] = {4,2,2,1};
__device__ const int c_tap0[4] = {0,4,6,8};
__device__ const int c_nmb[4]  = {69,66,66,64};       // ceil(M/128)
__device__ const int c_cnt[4]  = {276,264,264,256};   // nmb*4
__device__ const int c_dy[9] = {-1,-1,0,0, -1,0, 0,0, 0};
__device__ const int c_dx[9] = {-1,0,-1,0, 0,0, -1,0, 0};
__device__ const int c_ky[9] = {2,2,0,0, 2,0, 1,1, 1};
__device__ const int c_kx[9] = {2,0,2,0, 1,1, 2,0, 1};
__device__ const long c_poff[4] = {0, 4460544, 8785920, 13111296};

__device__ __forceinline__ float wave_red(float v) {
#pragma unroll
  for (int s = 32; s > 0; s >>= 1) v += __shfl_down(v, s);
  return v;
}

__device__ __forceinline__ void gl_lds16(const void* g, void* l) {
  __builtin_amdgcn_global_load_lds((const __attribute__((address_space(1))) void*)g,
                                   (__attribute__((address_space(3))) void*)l, 16, 0, 0);
}

__device__ __forceinline__ unsigned short bf16b(float f) {
  union { __hip_bfloat16 h; unsigned short u; } cv;
  cv.h = __float2bfloat16(f);
  return cv.u;
}

__device__ __forceinline__ float bfu(unsigned short u) {
  union { float f; unsigned u32; } c; c.u32 = ((unsigned)u) << 16; return c.f;
}

// bijective chunked XCD swizzle (m204)
__device__ __forceinline__ int xcd_chunk(int lb, int cnt) {
  const int q = cnt >> 3, r = cnt & 7;
  const int c = lb & 7, i = lb >> 3;
  return (c < r) ? c*(q+1) + i : r*(q+1) + (c - r)*q + i;
}

// ---------------- K1: wproc(512) + st0(64) + losses(512) + prep(1) + xs-border-zero(12) ----------------
__global__ __launch_bounds__(256) void k_big1(const float* __restrict__ W,
    float* __restrict__ wsq, float* __restrict__ wni,
    __hip_bfloat16* __restrict__ wrt,
    const float* __restrict__ style, const float* __restrict__ mod_w,
    const float* __restrict__ mod_b, float* __restrict__ st0,
    const float* __restrict__ co, const float* __restrict__ gate,
    const float* __restrict__ cluster, const float* __restrict__ tmpr,
    const float* __restrict__ mb_w, const float* __restrict__ mb_b,
    float* __restrict__ gr, float* __restrict__ sb,
    float* __restrict__ pacc, __hip_bfloat16* __restrict__ xs) {
  __shared__ float sh[8192];
  __shared__ float extra[8];
  const int bid = blockIdx.x, tid = threadIdx.x;
  const int lane = tid & 63, wv = tid >> 6;
  if (bid < 512) {
    const int o = bid;
    for (int j = tid; j < 4608; j += 256) sh[j] = W[(size_t)o*4608 + j];
    __syncthreads();
    float tot = 0.f;
#pragma unroll
    for (int half = 0; half < 2; half++) {
      const int i = tid + half*256;
      float s = 0.f;
#pragma unroll
      for (int k = 0; k < 9; k++) { float w = sh[i*9 + k]; s = fmaf(w, w, s); }
      wsq[o*512 + i] = s; tot += s;
#pragma unroll
      for (int tp = 0; tp < 9; tp++)
        wrt[((size_t)tp*512 + o)*512 + i] = __float2bfloat16(sh[i*9 + c_ky[tp]*3 + c_kx[tp]]);
    }
    tot = wave_red(tot);
    if (lane == 0) extra[wv] = tot;
    __syncthreads();
    if (tid == 0) wni[o] = 1.f / fmaxf(sqrtf(extra[0]+extra[1]+extra[2]+extra[3]), 1e-12f);
  } else if (bid < 576) {
    const int b = (bid - 512) >> 3, oc = (bid - 512) & 7;
    sh[tid] = style[b*1024 + 512 + tid];
    sh[tid + 256] = style[b*1024 + 768 + tid];
    __syncthreads();
#pragma unroll
    for (int rr = 0; rr < 16; rr++) {
      const int c = oc*64 + wv*16 + rr;
      const float* mw = mod_w + (size_t)c*512;
      float acc = 0.f;
#pragma unroll
      for (int it = 0; it < 8; it++) acc = fmaf(mw[lane + 64*it], sh[lane + 64*it], acc);
      acc = wave_red(acc);
      if (lane == 0) st0[b*512 + c] = acc*LIN_SCALE + mod_b[c];
    }
  } else if (bid < 1088) {
    // losses: recompute cl locally
    const int i = bid - 576;
    const float tt = 5.f / (1.f + expf(-tmpr[0]));
    const float gg = 1.f / (1.f + expf(-gate[0]));
    for (int j = tid; j < 512; j += 256) {
      float v[16]; float m = -1e30f;
#pragma unroll
      for (int g = 0; g < 16; g++) { v[g] = tt * cluster[g*512 + j]; m = fmaxf(m, v[g]); }
      float s = 0.f;
#pragma unroll
      for (int g = 0; g < 16; g++) { v[g] = expf(v[g] - m); s += v[g]; }
      float inv = 1.f / s;
#pragma unroll
      for (int g = 0; g < 16; g++) sh[g*512 + j] = v[g] * inv;
    }
    __syncthreads();
    float cli[16];
#pragma unroll
    for (int k = 0; k < 16; k++) cli[k] = sh[k*512 + i];
    float p1 = 0.f, p2 = 0.f;
    for (int j = tid; j < 512; j += 256) {
      float d = 0.f;
#pragma unroll
      for (int k = 0; k < 16; k++) d = fmaf(cli[k], sh[k*512 + j], d);
      float S = 1.f / (1.f + expf(-50.f*(co[i*512 + j] - gg)));
      float e = d - S;
      p1 = fmaf(e, e, p1); p2 += S;
    }
    p1 = wave_red(p1); p2 = wave_red(p2);
    if (lane == 0) { extra[wv] = p1; extra[4 + wv] = p2; }
    __syncthreads();
    if (tid == 0)  pacc[i]       = extra[0]+extra[1]+extra[2]+extra[3];
    if (tid == 64) pacc[512 + i] = extra[4]+extra[5]+extra[6]+extra[7];
  } else if (bid == 1088) {
    // prep: gr + sb
    const float tt = 5.f / (1.f + expf(-tmpr[0]));
#pragma unroll
    for (int h = 0; h < 2; h++) {
      const int c = tid + h*256;
      float v[16]; float m = -1e30f;
#pragma unroll
      for (int g = 0; g < 16; g++) { v[g] = tt * cluster[g*512 + c]; m = fmaxf(m, v[g]); }
      float s = 0.f;
#pragma unroll
      for (int g = 0; g < 16; g++) { v[g] = expf(v[g] - m); s += v[g]; }
      float inv = 1.f / s;
      float clv[16]; float m2 = -1e30f;
#pragma unroll
      for (int g = 0; g < 16; g++) { clv[g] = v[g]*inv; m2 = fmaxf(m2, 500.f*clv[g]); }
      float s2 = 0.f; float e2[16];
#pragma unroll
      for (int g = 0; g < 16; g++) { e2[g] = expf(500.f*clv[g] - m2); s2 += e2[g]; }
      float i2 = 1.f / s2;
#pragma unroll
      for (int g = 0; g < 16; g++) gr[g*512 + c] = rintf(e2[g]*i2) + 1e-6f;
    }
    for (int task = wv; task < 128; task += 4) {
      int b = task >> 4, g = task & 15;
      const float* s1 = style + b*1024;
      const float* mw = mb_w + g*512;
      float acc = 0.f;
#pragma unroll
      for (int it = 0; it < 8; it++) acc = fmaf(s1[lane + 64*it], mw[lane + 64*it], acc);
      acc = wave_red(acc);
      if (lane == 0) sb[b*16 + g] = acc*LIN_SCALE + mb_b[g];
    }
  } else {
    // zero the xs border ring (1.08 MB)
    const int id0 = (bid - 1089)*256 + tid;
    const float4 z = make_float4(0.f, 0.f, 0.f, 0.f);
    float4* xq = (float4*)xs;
#pragma unroll
    for (int it = 0; it < 22; ++it) {
      const int id = id0 + it*3072;
      const int c = id & 63;
      const int pb = id >> 6;
      const int b = pb / 132;
      const int pix = pb - b*132;
      int y, xx;
      if (pix < 34)       { y = 0;        xx = pix; }
      else if (pix < 68)  { y = 33;       xx = pix - 34; }
      else if (pix < 100) { y = pix - 67; xx = 0; }
      else                { y = pix - 99; xx = 33; }
      xq[((size_t)(b*34 + y)*34 + xx)*64 + c] = z;
    }
  }
}

// ---------------- K2: demod(64) + xsprep(1024) + loss-reduce(1); style-mix inline ----------------
__global__ __launch_bounds__(256) void k_big2(const float* __restrict__ st0,
    const float* __restrict__ gr, const float* __restrict__ sb,
    const float* __restrict__ wsq, float* __restrict__ dm,
    const float* __restrict__ x, __hip_bfloat16* __restrict__ xs,
    const float* __restrict__ pacc, float* __restrict__ out_tail) {
  __shared__ float L[64*65];
  __shared__ float red[16][4];
  __shared__ float inv[16];
  __shared__ float sbb[16];
  const int tid = threadIdx.x;
  const int lane = tid & 63, wv = tid >> 6;

  if (blockIdx.x == 1088) {
    float a = pacc[tid] + pacc[tid + 256];
    float b2 = pacc[512 + tid] + pacc[768 + tid];
    a = wave_red(a); b2 = wave_red(b2);
    if (lane == 0) { red[0][wv] = a; red[1][wv] = b2; }
    __syncthreads();
    if (tid == 0) {
      float p1 = red[0][0]+red[0][1]+red[0][2]+red[0][3];
      float p2 = red[1][0]+red[1][1]+red[1][2]+red[1][3];
      out_tail[0] = p1;
      float d = 16384.f - p2;
      out_tail[1] = d*d;
    }
    return;
  }

  const int b = (blockIdx.x < 64) ? (blockIdx.x >> 3) : ((blockIdx.x - 64) >> 7);
  float s0 = st0[b*512 + tid], s1 = st0[b*512 + 256 + tid];
  float g0[16], g1[16];
#pragma unroll
  for (int g = 0; g < 16; g++) { g0[g] = gr[g*512 + tid]; g1[g] = gr[g*512 + 256 + tid]; }
#pragma unroll
  for (int g = 0; g < 16; g++) {
    float a = g0[g]*s0, c = g1[g]*s1;
    float p = wave_red(a*a + c*c);
    if (lane == 0) red[g][wv] = p;
  }
  if (tid < 16) sbb[tid] = sb[b*16 + tid];
  __syncthreads();
  if (tid < 16) {
    float ttn = red[tid][0] + red[tid][1] + red[tid][2] + red[tid][3];
    inv[tid] = 1.f / fmaxf(sqrtf(ttn), 1e-12f);
  }
  __syncthreads();
  float f0 = 0.f, f1 = 0.f;
#pragma unroll
  for (int g = 0; g < 16; g++) {
    float w = inv[g]*sbb[g];
    f0 = fmaf(g0[g], w, f0); f1 = fmaf(g1[g], w, f1);
  }
  const float sn0 = s0*f0, sn1 = s1*f1;

  if (blockIdx.x < 64) {
    const int oc = blockIdx.x & 7;
    L[tid] = sn0*sn0;
    L[tid + 256] = sn1*sn1;
    __syncthreads();
#pragma unroll
    for (int rr = 0; rr < 16; rr++) {
      const int o = oc*64 + wv*16 + rr;
      const float* wp = wsq + (size_t)o*512;
      float acc = 0.f;
#pragma unroll
      for (int it = 0; it < 8; it++) acc = fmaf(wp[lane + 64*it], L[lane + 64*it], acc);
      acc = wave_red(acc);
      if (lane == 0) dm[b*512 + o] = rsqrtf((1.0f/4608.0f)*acc + 1e-8f);
    }
    return;
  }

  // xsprep: sts broadcast via L, save this thread's 2 scales, then tile x via float4
  L[tid] = sn0*SCALE;
  L[tid + 256] = sn1*SCALE;
  __syncthreads();
  const int id = blockIdx.x - 64;
  const int p0 = ((id >> 3) & 15) * 64;
  const int i0 = (id & 7) * 64;
  const int iw2 = (tid & 31) * 2, pw = tid >> 5;
  const float sv0 = L[i0 + iw2];
  const float sv1 = L[i0 + iw2 + 1];
  __syncthreads();
  const int cg = (tid & 15) * 4, ir = tid >> 4;
  const float* xp = x + ((size_t)b*512 + i0)*1024 + p0;
  float4 xv[4];
#pragma unroll
  for (int ii = 0; ii < 4; ii++) {
    const int i = ir + 16*ii;
    xv[ii] = *(const float4*)(xp + (size_t)i*1024 + cg);
  }
#pragma unroll
  for (int ii = 0; ii < 4; ii++) {
    const int i = ir + 16*ii;
    L[i*65 + cg + 0] = xv[ii].x;
    L[i*65 + cg + 1] = xv[ii].y;
    L[i*65 + cg + 2] = xv[ii].z;
    L[i*65 + cg + 3] = xv[ii].w;
  }
  __syncthreads();
#pragma unroll
  for (int pp = 0; pp < 8; pp++) {
    const int po = pw + 8*pp;
    const int pix = p0 + po;
    const int y = pix >> 5, xq = pix & 31;
    ushort2 w;
    w.x = bf16b(L[iw2*65 + po] * sv0);
    w.y = bf16b(L[(iw2+1)*65 + po] * sv1);
    *(ushort2*)((unsigned short*)xs + (((size_t)b*34 + (y+1))*34 + (xq+1))*512 + i0 + iw2) = w;
  }
}

// ---------------- K3: conv MFMA (1060) + gram MFMA (48), 1108 blocks ----------------
// Triple-buffered LDS, single barrier/step, counted vmcnt(4) (T3/T4). Gram reads wrt
// directly (Σ_tap wrt[tap]·wrt[tap]^T == wb·wb^T; taps enumerate all (ky,kx) once):
// wb buffer eliminated, gram B-stream L2-warm from conv on the same XCD.
// 3 tap-slices × 16 mn-quadrants = 48 blocks × 48 steps.
__global__ __launch_bounds__(256, 3) void k_mfma(
    const __hip_bfloat16* __restrict__ xs, const __hip_bfloat16* __restrict__ wrt,
    __hip_bfloat16* __restrict__ out1, float* __restrict__ pgram) {
  __shared__ __hip_bfloat16 smem[24576];
  const int fid = blockIdx.x;
  const int tid = threadIdx.x;
  const int lane = tid & 63, wv = tid >> 6;
  const int wm = (wv >> 1) << 6, wn = (wv & 1) << 6;
  const int col16 = lane & 15, quad = lane >> 4;
  const int colp = col16 ^ ((col16 >> 2) & 1);
  const int soff = (quad ^ (col16 & 3)) << 3;

  int aoff[4], boff[4];
#pragma unroll
  for (int t = 0; t < 4; t++) {
    aoff[t] = (wm + t*16 + colp)*32 + soff;
    boff[t] = 4096 + (wn + t*16 + colp)*32 + soff;
  }
  floatx4 acc[4][4];
#pragma unroll
  for (int i = 0; i < 4; i++)
#pragma unroll
    for (int j = 0; j < 4; j++) acc[i][j] = (floatx4){0.f, 0.f, 0.f, 0.f};

  if (fid >= 276 && fid < 324) {
    // ---- gram: slice ts sums taps 3ts..3ts+2 of wrt[tap] @ wrt[tap]^T ----
    const int g = xcd_chunk(fid - 276, 48);
    const int ts = g >> 4;
    const int mn = g & 15;
    const int m0 = (mn & 3) * 128, n0 = (mn >> 2) * 128;
    long abase[2], bbase[2]; int ldso[2];
#pragma unroll
    for (int r = 0; r < 2; r++) {
      const int idx = r*256 + tid;
      const int rowp = idx >> 2;
      const int row = rowp ^ ((rowp >> 2) & 1);
      const int kc = (((idx & 3) ^ (row & 3)) << 3);
      abase[r] = ((long)(ts*1536 + m0 + row))*512 + kc;
      bbase[r] = ((long)(ts*1536 + n0 + row))*512 + kc;
      ldso[r] = idx << 3;
    }
#define STAGE_GRAM(s_, lo_) do { \
      const long del_ = ((long)((s_) >> 4) << 18) + (((s_) & 15) << 5); \
      gl_lds16(wrt + (abase[0] + del_), smem + (lo_) + ldso[0]); \
      gl_lds16(wrt + (abase[1] + del_), smem + (lo_) + ldso[1]); \
      gl_lds16(wrt + (bbase[0] + del_), smem + (lo_) + 4096 + ldso[0]); \
      gl_lds16(wrt + (bbase[1] + del_), smem + (lo_) + 4096 + ldso[1]); \
    } while (0)
    STAGE_GRAM(0, 0);
    STAGE_GRAM(1, 8192);
    int loC = 0, loS = 16384;
    for (int s = 0; s < 48; ++s) {
      if (s + 1 < 48) asm volatile("s_waitcnt vmcnt(4)\n\ts_barrier" ::: "memory");
      else            asm volatile("s_waitcnt vmcnt(0)\n\ts_barrier" ::: "memory");
      if (s + 2 < 48) STAGE_GRAM(s + 2, loS);
      short8 af[4], bfr[4];
#pragma unroll
      for (int t = 0; t < 4; t++) {
        af[t]  = *(const short8*)(smem + loC + aoff[t]);
        bfr[t] = *(const short8*)(smem + loC + boff[t]);
      }
#pragma unroll
      for (int i = 0; i < 4; i++)
#pragma unroll
        for (int j = 0; j < 4; j++)
          acc[i][j] = __builtin_amdgcn_mfma_f32_16x16x32_bf16(af[i], bfr[j], acc[i][j], 0, 0, 0);
      loC = (loC == 16384) ? 0 : loC + 8192;
      loS = (loS == 16384) ? 0 : loS + 8192;
    }
    float* pg = pgram + (size_t)ts * 262144;
#pragma unroll
    for (int i = 0; i < 4; i++)
#pragma unroll
      for (int j = 0; j < 4; j++) {
        const int m = m0 + wm + i*16 + (quad << 2);
        const int n = n0 + wn + j*16 + col16;
#pragma unroll
        for (int r = 0; r < 4; r++) pg[(size_t)(m + r)*512 + n] = acc[i][j][r];
      }
    return;
  }

  // ---- conv ----
  int cls, lb;
  if (fid < 276)      { cls = 0; lb = fid; }
  else if (fid < 588) { cls = 1; lb = fid - 324; }
  else if (fid < 852) { cls = 2; lb = fid - 588; }
  else                { cls = 3; lb = fid - 852; }
  const int lg = xcd_chunk(lb, c_cnt[cls]);
  const int mb = lg >> 2, nb = lg & 3;
  const int xlim = c_xlim[cls];
  const int npix = c_ylim[cls] * xlim;
  const int M = NB * npix;
  const int m0 = mb * 128, n0 = nb * 128;
  const int t0 = c_tap0[cls];
  const int ntap = c_ntap[cls];

  long abase[2], bbase[2]; int ldso[2];
#pragma unroll
  for (int r = 0; r < 2; r++) {
    const int idx = r*256 + tid;
    const int rowp = idx >> 2;
    const int row = rowp ^ ((rowp >> 2) & 1);
    const int kc = (((idx & 3) ^ (row & 3)) << 3);
    int rm = m0 + row; if (rm >= M) rm = 0;
    const int b = rm / npix; const int rem = rm - b*npix;
    const int yy = rem / xlim; const int xx = rem - yy*xlim;
    abase[r] = ((long)(b*34 + yy + 1)*34 + (xx + 1))*512 + kc;
    bbase[r] = ((long)(t0*512 + n0 + row))*512 + kc;
    ldso[r] = idx << 3;
  }

  const int nst = ntap << 4;
#define STAGE_CONV(s_, lo_) do { \
    const int tap_ = t0 + ((s_) >> 4); \
    const long adel_ = (long)((c_dy[tap_]*34 + c_dx[tap_])*512); \
    const long bdel_ = (long)((s_) >> 4) << 18; \
    const int kk_ = ((s_) & 15) << 5; \
    gl_lds16(xs + (abase[0] + adel_ + kk_), smem + (lo_) + ldso[0]); \
    gl_lds16(xs + (abase[1] + adel_ + kk_), smem + (lo_) + ldso[1]); \
    gl_lds16(wrt + (bbase[0] + bdel_ + kk_), smem + (lo_) + 4096 + ldso[0]); \
    gl_lds16(wrt + (bbase[1] + bdel_ + kk_), smem + (lo_) + 4096 + ldso[1]); \
  } while (0)
  STAGE_CONV(0, 0);
  STAGE_CONV(1, 8192);
  int loC = 0, loS = 16384;
  for (int s = 0; s < nst; ++s) {
    if (s + 1 < nst) asm volatile("s_waitcnt vmcnt(4)\n\ts_barrier" ::: "memory");
    else             asm volatile("s_waitcnt vmcnt(0)\n\ts_barrier" ::: "memory");
    if (s + 2 < nst) STAGE_CONV(s + 2, loS);
    short8 af[4], bfr[4];
#pragma unroll
    for (int t = 0; t < 4; t++) {
      af[t]  = *(const short8*)(smem + loC + aoff[t]);
      bfr[t] = *(const short8*)(smem + loC + boff[t]);
    }
#pragma unroll
    for (int i = 0; i < 4; i++)
#pragma unroll
      for (int j = 0; j < 4; j++)
        acc[i][j] = __builtin_amdgcn_mfma_f32_16x16x32_bf16(af[i], bfr[j], acc[i][j], 0, 0, 0);
    loC = (loC == 16384) ? 0 : loC + 8192;
    loS = (loS == 16384) ? 0 : loS + 8192;
  }

  // epilogue: transpose 64 n-cols at a time through Ct[64][138]
  __syncthreads();
  __hip_bfloat16* plane = out1 + c_poff[cls];
#pragma unroll
  for (int h = 0; h < 2; h++) {
    if ((wv & 1) == h) {
#pragma unroll
      for (int i = 0; i < 4; i++) {
        const int mrow = wm + i*16 + (quad << 2);
#pragma unroll
        for (int j = 0; j < 4; j++) {
          const int ncl = j*16 + col16;
          ushort4 v;
          v.x = bf16b(acc[i][j][0]); v.y = bf16b(acc[i][j][1]);
          v.z = bf16b(acc[i][j][2]); v.w = bf16b(acc[i][j][3]);
          *(ushort4*)(smem + ncl*138 + mrow) = v;
        }
      }
    }
    __syncthreads();
#pragma unroll
    for (int it = 0; it < 4; it++) {
      const int c = it*256 + tid;
      const int ol = c >> 4, ml = (c & 15) << 3;
      const int mg = m0 + ml;
      if (mg < M) {
        const ushort4 v = *(const ushort4*)(smem + ol*138 + ml);
        *(ushort4*)(plane + (long)(n0 + h*64 + ol)*M + mg) = v;
      }
    }
    __syncthreads();
  }
}

// ---------------- K4: gram reduce+normalize (256) + blur+epilogue (4096) ----------------
__global__ __launch_bounds__(256) void k_blur(const __hip_bfloat16* __restrict__ out1,
    const float* __restrict__ dm, const float* __restrict__ noise,
    const float* __restrict__ nw, const float* __restrict__ fb, float* __restrict__ out,
    const float* __restrict__ pgram, const float* __restrict__ wni,
    float* __restrict__ co_out) {
  if (blockIdx.x < 256) {
    const int i4 = blockIdx.x*256 + threadIdx.x;
    float4 s = make_float4(0.f, 0.f, 0.f, 0.f);
#pragma unroll
    for (int z = 0; z < 3; z++) {
      const float4 v = ((const float4*)(pgram + (size_t)z*262144))[i4];
      s.x += v.x; s.y += v.y; s.z += v.z; s.w += v.w;
    }
    const float wm = wni[i4 >> 7];
    const float4 wn4 = ((const float4*)wni)[i4 & 127];
    float4 o;
    o.x = s.x*wm*wn4.x; o.y = s.y*wm*wn4.y; o.z = s.z*wm*wn4.z; o.w = s.w*wm*wn4.w;
    ((float4*)co_out)[i4] = o;
    return;
  }
  const int bo = blockIdx.x - 256;
  const int b = bo >> 9, o = bo & 511;
  __shared__ unsigned short L[65 * 68];   // [m][q+1], cols 0 and 66 zero guards
  __shared__ float Hs[67 * 64];           // horizontal pass, rows 0..66 = m -1..65
  const int tid = threadIdx.x;
  const unsigned short* p0 = (const unsigned short*)out1 + 0        + (long)o * 8712 + b * 1089;
  const unsigned short* p1 = (const unsigned short*)out1 + 4460544  + (long)o * 8448 + b * 1056;
  const unsigned short* p2 = (const unsigned short*)out1 + 8785920  + (long)o * 8448 + b * 1056;
  const unsigned short* p3 = (const unsigned short*)out1 + 13111296 + (long)o * 8192 + b * 1024;
  for (int m = tid; m < 65; m += 256) { L[m*68 + 0] = 0; L[m*68 + 66] = 0; }
  if (tid < 64) { Hs[tid] = 0.f; Hs[66*64 + tid] = 0.f; }
  for (int e = tid; e < 1089; e += 256) { int y = e / 33, x = e - 33*y; L[(2*y)*68 + 2*x + 1] = p0[e]; }
  for (int e2 = tid; e2 < 528; e2 += 256) {
    const int e = e2*2; const int y = e >> 5, x = e & 31;
    const ushort2 u = *(const ushort2*)(p1 + e);
    L[(2*y)*68 + 2*x + 2] = u.x; L[(2*y)*68 + 2*x + 4] = u.y;
  }
  for (int e = tid; e < 1056; e += 256) { int y = e / 33, x = e - 33*y; L[(2*y+1)*68 + 2*x + 1] = p2[e]; }
  for (int e2 = tid; e2 < 512; e2 += 256) {
    const int e = e2*2; const int y = e >> 5, x = e & 31;
    const ushort2 u = *(const ushort2*)(p3 + e);
    L[(2*y+1)*68 + 2*x + 2] = u.x; L[(2*y+1)*68 + 2*x + 4] = u.y;
  }
  __syncthreads();
  for (int e = tid; e < 4160; e += 256) {
    const int m = e >> 6, q = e & 63;
    const unsigned short* row = L + m*68 + q;
    Hs[(m+1)*64 + q] = 0.25f * (bfu(row[0]) + bfu(row[3])) + 0.75f * (bfu(row[1]) + bfu(row[2]));
  }
  __syncthreads();
  const float dmv = dm[bo];
  const float nwv = nw[0];
  const float bv = fb[o];
  const int qx = (tid & 15) << 2;
  const int py = tid >> 4;
  float* op = out + ((size_t)bo << 12);
  const float* npl = noise + ((size_t)b << 12);
#pragma unroll
  for (int pp = 0; pp < 4; pp++) {
    const int P = py + (pp << 4);
    const float4 h0 = *(const float4*)(Hs + (P    )*64 + qx);
    const float4 h1 = *(const float4*)(Hs + (P + 1)*64 + qx);
    const float4 h2 = *(const float4*)(Hs + (P + 2)*64 + qx);
    const float4 h3 = *(const float4*)(Hs + (P + 3)*64 + qx);
    const float4 n4 = *(const float4*)(npl + P*64 + qx);
    float4 ov;
    float s;
    s = 0.25f*(h0.x + h3.x) + 0.75f*(h1.x + h2.x);
    ov.x = fmaf(dmv, s, fmaf(nwv, n4.x, bv)); ov.x = (ov.x >= 0.f ? ov.x : 0.2f*ov.x) * 1.4142135623730951f;
    s = 0.25f*(h0.y + h3.y) + 0.75f*(h1.y + h2.y);
    ov.y = fmaf(dmv, s, fmaf(nwv, n4.y, bv)); ov.y = (ov.y >= 0.f ? ov.y : 0.2f*ov.y) * 1.4142135623730951f;
    s = 0.25f*(h0.z + h3.z) + 0.75f*(h1.z + h2.z);
    ov.z = fmaf(dmv, s, fmaf(nwv, n4.z, bv)); ov.z = (ov.z >= 0.f ? ov.z : 0.2f*ov.z) * 1.4142135623730951f;
    s = 0.25f*(h0.w + h3.w) + 0.75f*(h1.w + h2.w);
    ov.w = fmaf(dmv, s, fmaf(nwv, n4.w, bv)); ov.w = (ov.w >= 0.f ? ov.w : 0.2f*ov.w) * 1.4142135623730951f;
    *(float4*)(op + P*64 + qx) = ov;
  }
}

extern "C" void kernel_launch(void* const* d_in, const int* in_sizes, int n_in,
                              void* d_out, int out_size, void* d_ws, size_t ws_size,
                              hipStream_t stream) {
  const float* x       = (const float*)d_in[0];
  const float* co      = (const float*)d_in[1];
  const float* style   = (const float*)d_in[2];
  const float* noise   = (const float*)d_in[3];
  const float* W       = (const float*)d_in[4];
  const float* mb_w    = (const float*)d_in[5];
  const float* mb_b    = (const float*)d_in[6];
  const float* mod_w   = (const float*)d_in[7];
  const float* mod_b   = (const float*)d_in[8];
  const float* cluster = (const float*)d_in[9];
  const float* gate    = (const float*)d_in[10];
  const float* tmpr    = (const float*)d_in[11];
  const float* nw      = (const float*)d_in[12];
  const float* fb      = (const float*)d_in[13];
  float* out = (float*)d_out;
  char* ws = (char*)d_ws;

  __hip_bfloat16* xs   = (__hip_bfloat16*)(ws + O_XS);
  __hip_bfloat16* out1 = (__hip_bfloat16*)(ws + O_OUT1);
  __hip_bfloat16* wrt  = (__hip_bfloat16*)(ws + O_WRT);
  float* pgram = (float*)(ws + O_PG);
  float* wsq = (float*)(ws + O_WSQ);
  float* gr  = (float*)(ws + O_GR);
  float* sb  = (float*)(ws + O_SB);
  float* st0 = (float*)(ws + O_ST0);
  float* wni = (float*)(ws + O_WNI);
  float* dm  = (float*)(ws + O_DM);
  float* pacc = (float*)(ws + O_STS);

  k_big1<<<1101, 256, 0, stream>>>(W, wsq, wni, wrt,
                                   style, mod_w, mod_b, st0, co, gate,
                                   cluster, tmpr, mb_w, mb_b, gr, sb, pacc, xs);
  k_big2<<<1089, 256, 0, stream>>>(st0, gr, sb, wsq, dm, x, xs, pacc, out + OUT_L);
  k_mfma<<<1108, 256, 0, stream>>>(xs, wrt, out1, pgram);
  k_blur<<<4352, 256, 0, stream>>>(out1, dm, noise, nw, fb, out, pgram, wni, out + OUT_CO);
}